// Round 2
// baseline (110826.196 us; speedup 1.0000x reference)
//
#include <hip/hip_runtime.h>
#include <stdint.h>

typedef __bf16 bf16x8 __attribute__((ext_vector_type(8)));
typedef float  f32x4  __attribute__((ext_vector_type(4)));

#define NBLK 416

static __device__ __forceinline__ unsigned short f2bf(float f) {
  unsigned int u = __float_as_uint(f);
  u = u + 0x7fffu + ((u >> 16) & 1u);
  return (unsigned short)(u >> 16);
}
static __device__ __forceinline__ float bf2f(unsigned short h) {
  return __uint_as_float(((unsigned int)h) << 16);
}
static __device__ __forceinline__ float sigm(float x) {
  return 1.f / (1.f + __expf(-x));
}
static __device__ __forceinline__ float tanh_f(float x) {
  float ax = fabsf(x);
  float e = __expf(-2.f * ax);
  float t = (1.f - e) / (1.f + e);
  return copysignf(t, x);
}

// Device-scope epoch barrier: each block release-adds 1; all blocks wait until
// cnt >= target (= epoch * NBLK). Monotonic counter -> no reset race.
// Guard: on timeout, poison cnt so every present/future barrier releases
// (wrong answer, never a hang).
static __device__ __forceinline__ void gbar(int* bar, int target) {
  __syncthreads();
  if (threadIdx.x == 0) {
    __threadfence();
    __hip_atomic_fetch_add(bar, 1, __ATOMIC_RELEASE, __HIP_MEMORY_SCOPE_AGENT);
    int guard = 0;
    while (__hip_atomic_load(bar, __ATOMIC_ACQUIRE, __HIP_MEMORY_SCOPE_AGENT) < target) {
      __builtin_amdgcn_s_sleep(8);
      if (++guard > (1 << 22)) {
        __hip_atomic_fetch_add(bar, 1 << 29, __ATOMIC_RELEASE,
                               __HIP_MEMORY_SCOPE_AGENT);
        break;
      }
    }
  }
  __threadfence();
  __syncthreads();
}

// ---------------- weight packing (runs every launch; ws is re-poisoned) ----
__global__ void kPrep(const float* __restrict__ w4i, const float* __restrict__ w4h,
                      const float* __restrict__ b4i, const float* __restrict__ b4h,
                      const float* __restrict__ w5i, const float* __restrict__ w5h,
                      const float* __restrict__ b5i, const float* __restrict__ b5h,
                      const float* __restrict__ w1i, const float* __restrict__ w1h,
                      const float* __restrict__ b1i, const float* __restrict__ b1h,
                      const float* __restrict__ w2i, const float* __restrict__ w2h,
                      const float* __restrict__ b2i, const float* __restrict__ b2h,
                      const float* __restrict__ w3i, const float* __restrict__ w3h,
                      const float* __restrict__ b3i, const float* __restrict__ b3h,
                      unsigned short* __restrict__ W4, unsigned short* __restrict__ W5,
                      float* __restrict__ W1, float* __restrict__ W2, float* __restrict__ W3,
                      float* __restrict__ b4, float* __restrict__ b5,
                      float* __restrict__ b1, float* __restrict__ b2, float* __restrict__ b3) {
  int idx0 = blockIdx.x * blockDim.x + threadIdx.x;
  int stride = gridDim.x * blockDim.x;
  const int TOT = 3197328;
  for (int i = idx0; i < TOT; i += stride) {
    int i2 = i;
    if (i2 < 2662400) {
      int n = i2 / 832, k = i2 % 832;
      float v = (k < 20) ? w4i[n * 20 + k]
                         : ((k >= 24 && k < 824) ? w4h[n * 800 + (k - 24)] : 0.f);
      W4[i2] = f2bf(v);
      continue;
    }
    i2 -= 2662400;
    if (i2 < 475136) {
      int n = i2 / 928, k = i2 % 928;
      float v = (k < 800) ? w5i[n * 800 + k] : w5h[n * 128 + (k - 800)];
      W5[i2] = f2bf(v);
      continue;
    }
    i2 -= 475136;
    if (i2 < 46080) {
      int n = i2 / 192, k = i2 % 192;
      W1[i2] = (k < 128) ? w1i[n * 128 + k] : ((k < 188) ? w1h[n * 60 + (k - 128)] : 0.f);
      continue;
    }
    i2 -= 46080;
    if (i2 < 6400) {
      int n = i2 / 80, k = i2 % 80;
      W2[i2] = (k < 60) ? w2i[n * 60 + k] : w2h[n * 20 + (k - 60)];
      continue;
    }
    i2 -= 6400;
    if (i2 < 3200) {
      int n = i2 / 40, k = i2 % 40;
      W3[i2] = (k < 20) ? w3i[n * 20 + k] : w3h[n * 20 + (k - 20)];
      continue;
    }
    i2 -= 3200;
    if (i2 < 3200) { b4[i2] = b4i[i2] + b4h[i2]; continue; }
    i2 -= 3200;
    if (i2 < 512) { b5[i2] = b5i[i2] + b5h[i2]; continue; }
    i2 -= 512;
    if (i2 < 240) { b1[i2] = b1i[i2] + b1h[i2]; continue; }
    i2 -= 240;
    if (i2 < 80) { b2[i2] = b2i[i2] + b2h[i2]; continue; }
    i2 -= 80;
    b3[i2] = b3i[i2] + b3h[i2];
  }
}

__global__ void kZero(float* __restrict__ c2, float* __restrict__ c3,
                      unsigned int* __restrict__ h2, unsigned int* __restrict__ h3,
                      int* __restrict__ bar) {
  int idx = blockIdx.x * blockDim.x + threadIdx.x;
  int stride = gridDim.x * blockDim.x;
  for (int i = idx; i < 819200; i += stride) c2[i] = 0.f;
  for (int i = idx; i < 131072; i += stride) c3[i] = 0.f;
  for (int i = idx; i < 409600; i += stride) h2[i] = 0u;
  for (int i = idx; i < 65536; i += stride) h3[i] = 0u;
  if (idx < 64) bar[idx] = 0;
}

// ---------------- encoder: fc1 + fc21 fused, 4 batch rows / block ----------
__global__ __launch_bounds__(256, 2)
void kEnc(const float* __restrict__ x,
          const float* __restrict__ W1, const float* __restrict__ b1,
          const float* __restrict__ W2, const float* __restrict__ b2,
          const float* __restrict__ idW, const float* __restrict__ idb,
          float* __restrict__ hl30, float* __restrict__ cl30,
          float* __restrict__ out0, float* __restrict__ muOut) {
  __shared__ float xb[512];
  __shared__ float hb[240], cbb[240], h1b[240];
  __shared__ float h21[80], c21[80];
  __shared__ float g1[960], g2[320];
  const int tid = threadIdx.x;
  const int rowbase = blockIdx.x * 4;
  if (tid < 240) { hb[tid] = 0.f; cbb[tid] = 0.f; h1b[tid] = 0.f; }
  if (tid < 80) { h21[tid] = 0.f; c21[tid] = 0.f; }
  __syncthreads();
  for (int t = 0; t < 256; ++t) {
    const float* xs = x + ((size_t)t * 1024 + rowbase) * 128;
    xb[tid] = xs[tid];
    xb[tid + 256] = xs[tid + 256];
    __syncthreads();
    if (tid < 240) {
      const float* wr = W1 + tid * 192;
      float s0 = b1[tid], s1 = s0, s2 = s0, s3 = s0;
      for (int k = 0; k < 128; ++k) {
        float w = wr[k];
        s0 += w * xb[k]; s1 += w * xb[128 + k]; s2 += w * xb[256 + k]; s3 += w * xb[384 + k];
      }
      for (int k = 0; k < 60; ++k) {
        float w = wr[128 + k];
        s0 += w * hb[k]; s1 += w * hb[60 + k]; s2 += w * hb[120 + k]; s3 += w * hb[180 + k];
      }
      g1[tid] = s0; g1[240 + tid] = s1; g1[480 + tid] = s2; g1[720 + tid] = s3;
    }
    __syncthreads();
    if (tid < 240) {
      int b = tid / 60, j = tid % 60;
      const float* g = g1 + b * 240;
      float iv = sigm(g[j]), fv = sigm(g[60 + j]), gv = tanh_f(g[120 + j]), ov = sigm(g[180 + j]);
      float c = fv * cbb[b * 60 + j] + iv * gv;
      cbb[b * 60 + j] = c;
      float h = ov * tanh_f(c);
      hb[b * 60 + j] = h;
      h1b[b * 60 + j] = fmaxf(h, 0.f);
    }
    __syncthreads();
    if (tid < 80) {
      const float* wr = W2 + tid * 80;
      float s0 = b2[tid], s1 = s0, s2 = s0, s3 = s0;
      for (int k = 0; k < 60; ++k) {
        float w = wr[k];
        s0 += w * h1b[k]; s1 += w * h1b[60 + k]; s2 += w * h1b[120 + k]; s3 += w * h1b[180 + k];
      }
      for (int k = 0; k < 20; ++k) {
        float w = wr[60 + k];
        s0 += w * h21[k]; s1 += w * h21[20 + k]; s2 += w * h21[40 + k]; s3 += w * h21[60 + k];
      }
      g2[tid] = s0; g2[80 + tid] = s1; g2[160 + tid] = s2; g2[240 + tid] = s3;
    }
    __syncthreads();
    if (tid < 80) {
      int b = tid / 20, j = tid % 20;
      const float* g = g2 + b * 80;
      float iv = sigm(g[j]), fv = sigm(g[20 + j]), gv = tanh_f(g[40 + j]), ov = sigm(g[60 + j]);
      float c = fv * c21[b * 20 + j] + iv * gv;
      c21[b * 20 + j] = c;
      h21[b * 20 + j] = ov * tanh_f(c);
    }
    __syncthreads();
  }
  if (tid < 80) {
    int b = tid / 20, j = tid % 20;
    int gb = rowbase + b;
    float mu = h21[b * 20 + j];
    muOut[(size_t)gb * 20 + j] = mu;
    hl30[gb * 20 + j] = mu;
    cl30[gb * 20 + j] = c21[b * 20 + j];
    float s = idb[j];
    for (int k = 0; k < 20; ++k) s += h21[b * 20 + k] * idW[j * 20 + k];
    out0[gb * 20 + j] = s;
  }
}

// ---------------- persistent decoder: all 256 timesteps, one launch --------
// 416 blocks x 256 threads, NORMAL launch (no cooperative API). Phase 1 (all
// blocks): out/l3/stage/l4-MFMA (13 col-tiles x 32 row-tiles). gbar. Phase 2
// (blocks 0..127): l5-MFMA + output (4 x 32). gbar. LDS = 61952 B shared ->
// 2 blocks/CU, 416 <= 512 co-resident, barrier safe.
__global__ __launch_bounds__(256, 2)
void kDec(const unsigned short* __restrict__ W4, const float* __restrict__ b4,
          const unsigned short* __restrict__ W5, const float* __restrict__ b5,
          const float* __restrict__ W3, const float* __restrict__ b3,
          const float* __restrict__ dW, const float* __restrict__ db,
          const float* __restrict__ out0,
          float* __restrict__ hl3buf, float* __restrict__ cl3buf,
          unsigned short* __restrict__ h2buf, unsigned short* __restrict__ h3buf,
          float* __restrict__ c2, float* __restrict__ c3,
          float* __restrict__ dout, int* bar) {
  __shared__ __align__(16) unsigned short ls[32 * 968];  // 61952 B, both phases
  float* lsOut = (float*)ls;                   // 640 f32   (bytes 0..2560)
  float* lsGates = (float*)(ls + 1280);        // 2560 f32  (bytes 2560..12800)
  unsigned short* lsH3p = ls + 6400;           // 4096 u16  (bytes 12800..20992)
  float* lsHnew = (float*)(ls + 26880);        // 640 f32   (bytes 53760..56320)

  const int tid = threadIdx.x;
  const int blk = blockIdx.x;
  const int bx1 = blk % 13, by1 = blk / 13;    // phase-1 tile (cols, rows)
  const int rowbase1 = by1 * 32;
  const int cb = bx1 * 64;
  const int ncols = (cb + 64 <= 800) ? 64 : (800 - cb);
  const int w = tid >> 6, lane = tid & 63, quad = lane >> 4, l16 = lane & 15;

  // ---- loop-invariant phase-1 addressing ----
  const int jwl = w * 16;
  const bool act1 = (jwl < ncols);
  const int j4 = cb + jwl + l16;
  const unsigned short* Wp4 = W4 + (size_t)j4 * 832 + quad * 8;
  const unsigned short* A0 = ls + l16 * 840 + quad * 8;
  const unsigned short* A1 = ls + (16 + l16) * 840 + quad * 8;
  float bi4 = 0.f, bf4 = 0.f, bg4 = 0.f, bo4 = 0.f;
  if (act1) { bi4 = b4[j4]; bf4 = b4[800 + j4]; bg4 = b4[1600 + j4]; bo4 = b4[2400 + j4]; }

  // ---- loop-invariant phase-2 addressing ----
  const bool act2 = (blk < 128);
  const int rowbase2 = (blk >> 2) * 32;
  const int colbase2 = (blk & 3) * 32;
  const int mh = w >> 1, jh = w & 1;
  const int j5 = colbase2 + jh * 16 + l16;
  const unsigned short* Wp5 = W5 + (size_t)j5 * 928 + quad * 8;
  const unsigned short* Ap5 = ls + (mh * 16 + l16) * 968 + quad * 8;
  float bi5 = 0.f, bf5 = 0.f, bg5 = 0.f, bo5 = 0.f;
  if (act2) { bi5 = b5[j5]; bf5 = b5[128 + j5]; bg5 = b5[256 + j5]; bo5 = b5[384 + j5]; }

  for (int t = 0; t < 256; ++t) {
    const int p = t & 1;
    const unsigned short* h2_in = h2buf + (size_t)p * 819200;
    unsigned short* h2_out = h2buf + (size_t)(1 - p) * 819200;
    const unsigned short* h3_in = h3buf + (size_t)p * 131072;
    unsigned short* h3_out = h3buf + (size_t)(1 - p) * 131072;
    const float* hl3_in = hl3buf + (size_t)p * 20480;
    float* hl3_out = hl3buf + (size_t)(1 - p) * 20480;
    const float* cl3_in = cl3buf + (size_t)p * 20480;
    float* cl3_out = cl3buf + (size_t)(1 - p) * 20480;

    // ================= phase 1: down + l3 (scalar) + l4 (MFMA) =============
    if (t > 0) {  // stage h3_prev tile (32x128 bf16, contiguous)
      const uint4* src = (const uint4*)(h3_in + (size_t)rowbase1 * 128);
      uint4* dst = (uint4*)lsH3p;
      for (int i = tid; i < 512; i += 256) dst[i] = src[i];
    }
    __syncthreads();
    if (t == 0) {
      for (int i = tid; i < 640; i += 256) {
        int bb = i / 20, k = i % 20;
        lsOut[i] = out0[(size_t)(rowbase1 + bb) * 20 + k];
      }
    } else {  // out = h3_prev @ dW^T + db
      for (int i = tid; i < 640; i += 256) {
        int bb = i / 20, k = i % 20;
        const float* wr = dW + k * 128;
        const unsigned short* hr = lsH3p + bb * 128;
        float s = db[k];
        for (int jj = 0; jj < 128; ++jj) s += bf2f(hr[jj]) * wr[jj];
        lsOut[i] = s;
      }
    }
    __syncthreads();
    for (int i = tid; i < 2560; i += 256) {  // l3 gates, K = [out(20)|hl3(20)]
      int bb = i / 80, n = i % 80;
      const float* wr = W3 + n * 40;
      const float* ob = lsOut + bb * 20;
      const float* hp = hl3_in + (size_t)(rowbase1 + bb) * 20;
      float s = b3[n];
      for (int k = 0; k < 20; ++k) s += ob[k] * wr[k];
      for (int k = 0; k < 20; ++k) s += hp[k] * wr[20 + k];
      lsGates[i] = s;
    }
    __syncthreads();
    for (int i = tid; i < 640; i += 256) {  // l3 cell
      int bb = i / 20, jj = i % 20;
      const float* g = lsGates + bb * 80;
      float iv = sigm(g[jj]), fv = sigm(g[20 + jj]);
      float gv = tanh_f(g[40 + jj]), ov = sigm(g[60 + jj]);
      float c = fv * cl3_in[(size_t)(rowbase1 + bb) * 20 + jj] + iv * gv;
      float h = ov * tanh_f(c);
      lsHnew[i] = h;
      if (bx1 == 0) {
        hl3_out[(size_t)(rowbase1 + bb) * 20 + jj] = h;
        cl3_out[(size_t)(rowbase1 + bb) * 20 + jj] = c;
      }
    }
    __syncthreads();
    // stage A: cols 0..19 = h_new (bf16), 20..23 = 0, 24..823 = h2_prev, 824.. = 0
    for (int i = tid; i < 3200; i += 256) {
      int bb = i / 100, ss = i % 100;
      *(uint4*)(ls + bb * 840 + 24 + ss * 8) =
          *(const uint4*)(h2_in + (size_t)(rowbase1 + bb) * 800 + ss * 8);
    }
    for (int i = tid; i < 640; i += 256) {
      int bb = i / 20, jj = i % 20;
      ls[bb * 840 + jj] = f2bf(lsHnew[i]);
    }
    for (int i = tid; i < 640; i += 256) {
      int bb = i / 20, z = i % 20;
      int col = (z < 4) ? (20 + z) : (820 + z);
      ls[bb * 840 + col] = 0;
    }
    __syncthreads();
    if (act1) {
      f32x4 acc[2][4];
#pragma unroll
      for (int mt = 0; mt < 2; ++mt)
#pragma unroll
        for (int g = 0; g < 4; ++g) acc[mt][g] = (f32x4){0.f, 0.f, 0.f, 0.f};
      for (int kc = 0; kc < 26; ++kc) {
        const int ko = kc * 32;
        bf16x8 a0 = *(const bf16x8*)(A0 + ko);
        bf16x8 a1 = *(const bf16x8*)(A1 + ko);
        bf16x8 bv0 = *(const bf16x8*)(Wp4 + (size_t)0 * 665600 + ko);
        bf16x8 bv1 = *(const bf16x8*)(Wp4 + (size_t)1 * 665600 + ko);
        bf16x8 bv2 = *(const bf16x8*)(Wp4 + (size_t)2 * 665600 + ko);
        bf16x8 bv3 = *(const bf16x8*)(Wp4 + (size_t)3 * 665600 + ko);
        acc[0][0] = __builtin_amdgcn_mfma_f32_16x16x32_bf16(a0, bv0, acc[0][0], 0, 0, 0);
        acc[1][0] = __builtin_amdgcn_mfma_f32_16x16x32_bf16(a1, bv0, acc[1][0], 0, 0, 0);
        acc[0][1] = __builtin_amdgcn_mfma_f32_16x16x32_bf16(a0, bv1, acc[0][1], 0, 0, 0);
        acc[1][1] = __builtin_amdgcn_mfma_f32_16x16x32_bf16(a1, bv1, acc[1][1], 0, 0, 0);
        acc[0][2] = __builtin_amdgcn_mfma_f32_16x16x32_bf16(a0, bv2, acc[0][2], 0, 0, 0);
        acc[1][2] = __builtin_amdgcn_mfma_f32_16x16x32_bf16(a1, bv2, acc[1][2], 0, 0, 0);
        acc[0][3] = __builtin_amdgcn_mfma_f32_16x16x32_bf16(a0, bv3, acc[0][3], 0, 0, 0);
        acc[1][3] = __builtin_amdgcn_mfma_f32_16x16x32_bf16(a1, bv3, acc[1][3], 0, 0, 0);
      }
#pragma unroll
      for (int mt = 0; mt < 2; ++mt) {
#pragma unroll
        for (int r = 0; r < 4; ++r) {
          int bg = rowbase1 + mt * 16 + quad * 4 + r;
          float iv = sigm(acc[mt][0][r] + bi4);
          float fv = sigm(acc[mt][1][r] + bf4);
          float gv = tanh_f(acc[mt][2][r] + bg4);
          float ov = sigm(acc[mt][3][r] + bo4);
          size_t ix = (size_t)bg * 800 + j4;
          float c = fv * c2[ix] + iv * gv;
          c2[ix] = c;
          h2_out[ix] = f2bf(ov * tanh_f(c));
        }
      }
    }
    gbar(bar, (2 * t + 1) * NBLK);

    // ================= phase 2: l5 (MFMA) + output write ===================
    if (act2) {
      for (int i = tid; i < 3200; i += 256) {
        int bb = i / 100, ss = i % 100;
        *(uint4*)(ls + bb * 968 + ss * 8) =
            *(const uint4*)(h2_out + (size_t)(rowbase2 + bb) * 800 + ss * 8);
      }
      for (int i = tid; i < 512; i += 256) {
        int bb = i / 16, ss = i % 16;
        *(uint4*)(ls + bb * 968 + 800 + ss * 8) =
            *(const uint4*)(h3_in + (size_t)(rowbase2 + bb) * 128 + ss * 8);
      }
      for (int i = tid; i < 1280; i += 256) {
        int bb = i / 40, z = i % 40;
        ls[bb * 968 + 928 + z] = 0;
      }
      __syncthreads();
      f32x4 acc[4];
#pragma unroll
      for (int g = 0; g < 4; ++g) acc[g] = (f32x4){0.f, 0.f, 0.f, 0.f};
      for (int kc = 0; kc < 29; ++kc) {
        const int ko = kc * 32;
        bf16x8 a = *(const bf16x8*)(Ap5 + ko);
        bf16x8 bv0 = *(const bf16x8*)(Wp5 + (size_t)0 * 118784 + ko);
        bf16x8 bv1 = *(const bf16x8*)(Wp5 + (size_t)1 * 118784 + ko);
        bf16x8 bv2 = *(const bf16x8*)(Wp5 + (size_t)2 * 118784 + ko);
        bf16x8 bv3 = *(const bf16x8*)(Wp5 + (size_t)3 * 118784 + ko);
        acc[0] = __builtin_amdgcn_mfma_f32_16x16x32_bf16(a, bv0, acc[0], 0, 0, 0);
        acc[1] = __builtin_amdgcn_mfma_f32_16x16x32_bf16(a, bv1, acc[1], 0, 0, 0);
        acc[2] = __builtin_amdgcn_mfma_f32_16x16x32_bf16(a, bv2, acc[2], 0, 0, 0);
        acc[3] = __builtin_amdgcn_mfma_f32_16x16x32_bf16(a, bv3, acc[3], 0, 0, 0);
      }
#pragma unroll
      for (int r = 0; r < 4; ++r) {
        int bg = rowbase2 + mh * 16 + quad * 4 + r;
        float iv = sigm(acc[0][r] + bi5);
        float fv = sigm(acc[1][r] + bf5);
        float gv = tanh_f(acc[2][r] + bg5);
        float ov = sigm(acc[3][r] + bo5);
        size_t ix = (size_t)bg * 128 + j5;
        float c = fv * c3[ix] + iv * gv;
        c3[ix] = c;
        float h = ov * tanh_f(c);
        dout[(size_t)t * 131072 + ix] = h;
        h3_out[ix] = f2bf(h);
      }
    }
    gbar(bar, (2 * t + 2) * NBLK);
  }
}

extern "C" void kernel_launch(void* const* d_in, const int* in_sizes, int n_in,
                              void* d_out, int out_size, void* d_ws, size_t ws_size,
                              hipStream_t stream) {
  (void)in_sizes; (void)n_in; (void)out_size; (void)ws_size;
  const float* x   = (const float*)d_in[0];
  const float* w1i = (const float*)d_in[1];
  const float* w1h = (const float*)d_in[2];
  const float* b1i = (const float*)d_in[3];
  const float* b1h = (const float*)d_in[4];
  const float* w2i = (const float*)d_in[5];
  const float* w2h = (const float*)d_in[6];
  const float* b2i = (const float*)d_in[7];
  const float* b2h = (const float*)d_in[8];
  const float* w3i = (const float*)d_in[9];
  const float* w3h = (const float*)d_in[10];
  const float* b3i = (const float*)d_in[11];
  const float* b3h = (const float*)d_in[12];
  const float* w4i = (const float*)d_in[13];
  const float* w4h = (const float*)d_in[14];
  const float* b4i = (const float*)d_in[15];
  const float* b4h = (const float*)d_in[16];
  const float* w5i = (const float*)d_in[17];
  const float* w5h = (const float*)d_in[18];
  const float* b5i = (const float*)d_in[19];
  const float* b5h = (const float*)d_in[20];
  const float* idW = (const float*)d_in[21];
  const float* idb = (const float*)d_in[22];
  const float* dW  = (const float*)d_in[23];
  const float* db  = (const float*)d_in[24];
  float* out = (float*)d_out;

  char* ws = (char*)d_ws;
  size_t off = 0;
  auto alloc = [&](size_t bytes) -> void* {
    void* p = ws + off;
    off = (off + bytes + 255) & ~(size_t)255;
    return p;
  };
  unsigned short* W4 = (unsigned short*)alloc(3200 * 832 * 2);
  unsigned short* W5 = (unsigned short*)alloc(512 * 928 * 2);
  float* W1 = (float*)alloc(240 * 192 * 4);
  float* W2 = (float*)alloc(80 * 80 * 4);
  float* W3 = (float*)alloc(80 * 40 * 4);
  float* b4 = (float*)alloc(3200 * 4);
  float* b5 = (float*)alloc(512 * 4);
  float* b1 = (float*)alloc(240 * 4);
  float* b2 = (float*)alloc(80 * 4);
  float* b3 = (float*)alloc(80 * 4);
  unsigned short* h2buf = (unsigned short*)alloc(2 * 1024 * 800 * 2);
  unsigned short* h3buf = (unsigned short*)alloc(2 * 1024 * 128 * 2);
  float* c2 = (float*)alloc(1024 * 800 * 4);
  float* c3 = (float*)alloc(1024 * 128 * 4);
  float* hl3 = (float*)alloc(2 * 1024 * 20 * 4);
  float* cl3 = (float*)alloc(2 * 1024 * 20 * 4);
  float* out0 = (float*)alloc(1024 * 20 * 4);
  int* bar = (int*)alloc(256);

  kPrep<<<dim3(4096), dim3(256), 0, stream>>>(
      w4i, w4h, b4i, b4h, w5i, w5h, b5i, b5h, w1i, w1h, b1i, b1h,
      w2i, w2h, b2i, b2h, w3i, w3h, b3i, b3h,
      W4, W5, W1, W2, W3, b4, b5, b1, b2, b3);
  kZero<<<dim3(2048), dim3(256), 0, stream>>>(c2, c3, (unsigned int*)h2buf,
                                              (unsigned int*)h3buf, bar);
  kEnc<<<dim3(256), dim3(256), 0, stream>>>(x, W1, b1, W2, b2, idW, idb,
                                            hl3, cl3, out0, out + 33554432);
  kDec<<<dim3(NBLK), dim3(256), 0, stream>>>(
      W4, b4, W5, b5, W3, b3, dW, db, out0, hl3, cl3,
      h2buf, h3buf, c2, c3, out, bar);
}

// Round 4
// 88553.723 us; speedup vs baseline: 1.2515x; 1.2515x over previous
//
#include <hip/hip_runtime.h>
#include <stdint.h>

typedef __bf16 bf16x8 __attribute__((ext_vector_type(8)));
typedef float  f32x4  __attribute__((ext_vector_type(4)));

#define SPIN_GUARD (1 << 16)

static __device__ __forceinline__ unsigned short f2bf(float f) {
  unsigned int u = __float_as_uint(f);
  u = u + 0x7fffu + ((u >> 16) & 1u);
  return (unsigned short)(u >> 16);
}
static __device__ __forceinline__ float bf2f(unsigned short h) {
  return __uint_as_float(((unsigned int)h) << 16);
}
static __device__ __forceinline__ float sigm(float x) {
  return 1.f / (1.f + __expf(-x));
}
static __device__ __forceinline__ float tanh_f(float x) {
  float ax = fabsf(x);
  float e = __expf(-2.f * ax);
  float t = (1.f - e) / (1.f + e);
  return copysignf(t, x);
}

// ---------------- weight packing (runs every launch; ws is re-poisoned) ----
__global__ void kPrep(const float* __restrict__ w4i, const float* __restrict__ w4h,
                      const float* __restrict__ b4i, const float* __restrict__ b4h,
                      const float* __restrict__ w5i, const float* __restrict__ w5h,
                      const float* __restrict__ b5i, const float* __restrict__ b5h,
                      const float* __restrict__ w1i, const float* __restrict__ w1h,
                      const float* __restrict__ b1i, const float* __restrict__ b1h,
                      const float* __restrict__ w2i, const float* __restrict__ w2h,
                      const float* __restrict__ b2i, const float* __restrict__ b2h,
                      const float* __restrict__ w3i, const float* __restrict__ w3h,
                      const float* __restrict__ b3i, const float* __restrict__ b3h,
                      unsigned short* __restrict__ W4, unsigned short* __restrict__ W5,
                      float* __restrict__ W1, float* __restrict__ W2, float* __restrict__ W3,
                      float* __restrict__ b4, float* __restrict__ b5,
                      float* __restrict__ b1, float* __restrict__ b2, float* __restrict__ b3) {
  int idx0 = blockIdx.x * blockDim.x + threadIdx.x;
  int stride = gridDim.x * blockDim.x;
  const int TOT = 3197328;
  for (int i = idx0; i < TOT; i += stride) {
    int i2 = i;
    if (i2 < 2662400) {
      int n = i2 / 832, k = i2 % 832;
      float v = (k < 20) ? w4i[n * 20 + k]
                         : ((k >= 24 && k < 824) ? w4h[n * 800 + (k - 24)] : 0.f);
      W4[i2] = f2bf(v);
      continue;
    }
    i2 -= 2662400;
    if (i2 < 475136) {
      int n = i2 / 928, k = i2 % 928;
      float v = (k < 800) ? w5i[n * 800 + k] : w5h[n * 128 + (k - 800)];
      W5[i2] = f2bf(v);
      continue;
    }
    i2 -= 475136;
    if (i2 < 46080) {
      int n = i2 / 192, k = i2 % 192;
      W1[i2] = (k < 128) ? w1i[n * 128 + k] : ((k < 188) ? w1h[n * 60 + (k - 128)] : 0.f);
      continue;
    }
    i2 -= 46080;
    if (i2 < 6400) {
      int n = i2 / 80, k = i2 % 80;
      W2[i2] = (k < 60) ? w2i[n * 60 + k] : w2h[n * 20 + (k - 60)];
      continue;
    }
    i2 -= 6400;
    if (i2 < 3200) {
      int n = i2 / 40, k = i2 % 40;
      W3[i2] = (k < 20) ? w3i[n * 20 + k] : w3h[n * 20 + (k - 20)];
      continue;
    }
    i2 -= 3200;
    if (i2 < 3200) { b4[i2] = b4i[i2] + b4h[i2]; continue; }
    i2 -= 3200;
    if (i2 < 512) { b5[i2] = b5i[i2] + b5h[i2]; continue; }
    i2 -= 512;
    if (i2 < 240) { b1[i2] = b1i[i2] + b1h[i2]; continue; }
    i2 -= 240;
    if (i2 < 80) { b2[i2] = b2i[i2] + b2h[i2]; continue; }
    i2 -= 80;
    b3[i2] = b3i[i2] + b3h[i2];
  }
}

__global__ void kZero(float* __restrict__ c2, float* __restrict__ c3,
                      unsigned int* __restrict__ h2, unsigned int* __restrict__ h3,
                      int* __restrict__ flags) {
  int idx = blockIdx.x * blockDim.x + threadIdx.x;
  int stride = gridDim.x * blockDim.x;
  for (int i = idx; i < 819200; i += stride) c2[i] = 0.f;
  for (int i = idx; i < 131072; i += stride) c3[i] = 0.f;
  for (int i = idx; i < 409600; i += stride) h2[i] = 0u;
  for (int i = idx; i < 65536; i += stride) h3[i] = 0u;
  for (int i = idx; i < 8704; i += stride) flags[i] = 0;
}

// ---------------- encoder: fc1 + fc21 fused, 4 batch rows / block ----------
__global__ __launch_bounds__(256, 2)
void kEnc(const float* __restrict__ x,
          const float* __restrict__ W1, const float* __restrict__ b1,
          const float* __restrict__ W2, const float* __restrict__ b2,
          const float* __restrict__ idW, const float* __restrict__ idb,
          float* __restrict__ hl30, float* __restrict__ cl30,
          float* __restrict__ out0, float* __restrict__ muOut) {
  __shared__ float xb[512];
  __shared__ float hb[240], cbb[240], h1b[240];
  __shared__ float h21[80], c21[80];
  __shared__ float g1[960], g2[320];
  const int tid = threadIdx.x;
  const int rowbase = blockIdx.x * 4;
  if (tid < 240) { hb[tid] = 0.f; cbb[tid] = 0.f; h1b[tid] = 0.f; }
  if (tid < 80) { h21[tid] = 0.f; c21[tid] = 0.f; }
  __syncthreads();
  for (int t = 0; t < 256; ++t) {
    const float* xs = x + ((size_t)t * 1024 + rowbase) * 128;
    xb[tid] = xs[tid];
    xb[tid + 256] = xs[tid + 256];
    __syncthreads();
    if (tid < 240) {
      const float* wr = W1 + tid * 192;
      float s0 = b1[tid], s1 = s0, s2 = s0, s3 = s0;
      for (int k = 0; k < 128; ++k) {
        float w = wr[k];
        s0 += w * xb[k]; s1 += w * xb[128 + k]; s2 += w * xb[256 + k]; s3 += w * xb[384 + k];
      }
      for (int k = 0; k < 60; ++k) {
        float w = wr[128 + k];
        s0 += w * hb[k]; s1 += w * hb[60 + k]; s2 += w * hb[120 + k]; s3 += w * hb[180 + k];
      }
      g1[tid] = s0; g1[240 + tid] = s1; g1[480 + tid] = s2; g1[720 + tid] = s3;
    }
    __syncthreads();
    if (tid < 240) {
      int b = tid / 60, j = tid % 60;
      const float* g = g1 + b * 240;
      float iv = sigm(g[j]), fv = sigm(g[60 + j]), gv = tanh_f(g[120 + j]), ov = sigm(g[180 + j]);
      float c = fv * cbb[b * 60 + j] + iv * gv;
      cbb[b * 60 + j] = c;
      float h = ov * tanh_f(c);
      hb[b * 60 + j] = h;
      h1b[b * 60 + j] = fmaxf(h, 0.f);
    }
    __syncthreads();
    if (tid < 80) {
      const float* wr = W2 + tid * 80;
      float s0 = b2[tid], s1 = s0, s2 = s0, s3 = s0;
      for (int k = 0; k < 60; ++k) {
        float w = wr[k];
        s0 += w * h1b[k]; s1 += w * h1b[60 + k]; s2 += w * h1b[120 + k]; s3 += w * h1b[180 + k];
      }
      for (int k = 0; k < 20; ++k) {
        float w = wr[60 + k];
        s0 += w * h21[k]; s1 += w * h21[20 + k]; s2 += w * h21[40 + k]; s3 += w * h21[60 + k];
      }
      g2[tid] = s0; g2[80 + tid] = s1; g2[160 + tid] = s2; g2[240 + tid] = s3;
    }
    __syncthreads();
    if (tid < 80) {
      int b = tid / 20, j = tid % 20;
      const float* g = g2 + b * 80;
      float iv = sigm(g[j]), fv = sigm(g[20 + j]), gv = tanh_f(g[40 + j]), ov = sigm(g[60 + j]);
      float c = fv * c21[b * 20 + j] + iv * gv;
      c21[b * 20 + j] = c;
      h21[b * 20 + j] = ov * tanh_f(c);
    }
    __syncthreads();
  }
  if (tid < 80) {
    int b = tid / 20, j = tid % 20;
    int gb = rowbase + b;
    float mu = h21[b * 20 + j];
    muOut[(size_t)gb * 20 + j] = mu;
    hl30[gb * 20 + j] = mu;
    cl30[gb * 20 + j] = c21[b * 20 + j];
    float s = idb[j];
    for (int k = 0; k < 20; ++k) s += h21[b * 20 + k] * idW[j * 20 + k];
    out0[gb * 20 + j] = s;
  }
}

// ---------------- persistent decoder: per-row-group flag sync --------------
// grid = 512 blocks (32 row-groups x 16 slots; slots 13..15 exit). Block
// (g, c): phase 1 = l4 col-tile c (64 cols) for rows g*32..+31. Blocks c<4
// additionally run phase 2 (l5, 32 h3-cols each). Sync is PER GROUP:
// 13 A-flags (ph1 done) + 4 B-flags (ph2 done), each on its own 64B line.
// No cross-group dependency exists (all state is row-local), so groups run
// desynchronized. blockIdx = g*16+c pins col-tile c to XCD c%8 (W4 slice
// ~850KB becomes L2-resident). 512 blocks x 62KB LDS = 2/CU, all resident.
__global__ __launch_bounds__(256, 2)
void kDec(const unsigned short* __restrict__ W4, const float* __restrict__ b4,
          const unsigned short* __restrict__ W5, const float* __restrict__ b5,
          const float* __restrict__ W3, const float* __restrict__ b3,
          const float* __restrict__ dW, const float* __restrict__ db,
          const float* __restrict__ out0,
          float* __restrict__ hl3buf, float* __restrict__ cl3buf,
          unsigned short* __restrict__ h2buf, unsigned short* __restrict__ h3buf,
          float* __restrict__ c2, float* __restrict__ c3,
          float* __restrict__ dout, int* flags) {
  const int blk = blockIdx.x;
  const int g = blk >> 4;      // row-group 0..31
  const int c = blk & 15;      // col-slot 0..15
  if (c >= 13) return;         // ghost slot (XCD-pinning pad)

  __shared__ __align__(16) unsigned short ls[32 * 968];  // 61952 B, both phases
  float* lsOut = (float*)ls;                   // 640 f32   (bytes 0..2560)
  float* lsGates = (float*)(ls + 1280);        // 2560 f32  (bytes 2560..12800)
  unsigned short* lsH3p = ls + 6400;           // 4096 u16  (bytes 12800..20992)
  float* lsHnew = (float*)(ls + 26880);        // 640 f32   (bytes 53760..56320)

  const int tid = threadIdx.x;
  const int rowbase1 = g * 32;
  const int cb = c * 64;
  const int ncols = (cb + 64 <= 800) ? 64 : (800 - cb);
  const int w = tid >> 6, lane = tid & 63, quad = lane >> 4, l16 = lane & 15;

  // ---- loop-invariant phase-1 addressing ----
  const int jwl = w * 16;
  const bool act1 = (jwl < ncols);
  const int j4 = cb + jwl + l16;
  const unsigned short* Wp4 = W4 + (size_t)j4 * 832 + quad * 8;
  const unsigned short* A0 = ls + l16 * 840 + quad * 8;
  const unsigned short* A1 = ls + (16 + l16) * 840 + quad * 8;
  float bi4 = 0.f, bf4 = 0.f, bg4 = 0.f, bo4 = 0.f;
  if (act1) { bi4 = b4[j4]; bf4 = b4[800 + j4]; bg4 = b4[1600 + j4]; bo4 = b4[2400 + j4]; }

  // ---- loop-invariant phase-2 addressing (blocks c<4 of each group) ----
  const bool act2 = (c < 4);
  const int rowbase2 = rowbase1;
  const int colbase2 = c * 32;
  const int mh = w >> 1, jh = w & 1;
  const int j5 = colbase2 + jh * 16 + l16;
  const unsigned short* Wp5 = W5 + (size_t)j5 * 928 + quad * 8;
  const unsigned short* Ap5 = ls + (mh * 16 + l16) * 968 + quad * 8;
  float bi5 = 0.f, bf5 = 0.f, bg5 = 0.f, bo5 = 0.f;
  if (act2) { bi5 = b5[j5]; bf5 = b5[128 + j5]; bg5 = b5[256 + j5]; bo5 = b5[384 + j5]; }

  int* fA = flags + (size_t)(g * 17) * 16;        // 13 A-flags, 64B apart
  int* fB = flags + (size_t)(g * 17 + 13) * 16;   // 4 B-flags, 64B apart

  for (int t = 0; t < 256; ++t) {
    const int p = t & 1;
    const unsigned short* h2_in = h2buf + (size_t)p * 819200;
    unsigned short* h2_out = h2buf + (size_t)(1 - p) * 819200;
    const unsigned short* h3_in = h3buf + (size_t)p * 131072;
    unsigned short* h3_out = h3buf + (size_t)(1 - p) * 131072;
    const float* hl3_in = hl3buf + (size_t)p * 20480;
    float* hl3_out = hl3buf + (size_t)(1 - p) * 20480;
    const float* cl3_in = cl3buf + (size_t)p * 20480;
    float* cl3_out = cl3buf + (size_t)(1 - p) * 20480;

    // ================= phase 1: down + l3 (scalar) + l4 (MFMA) =============
    if (t > 0) {  // stage h3_prev tile (32x128 bf16, contiguous)
      const uint4* src = (const uint4*)(h3_in + (size_t)rowbase1 * 128);
      uint4* dst = (uint4*)lsH3p;
      for (int i = tid; i < 512; i += 256) dst[i] = src[i];
    }
    __syncthreads();
    if (t == 0) {
      for (int i = tid; i < 640; i += 256) {
        int bb = i / 20, k = i % 20;
        lsOut[i] = out0[(size_t)(rowbase1 + bb) * 20 + k];
      }
    } else {  // out = h3_prev @ dW^T + db
      for (int i = tid; i < 640; i += 256) {
        int bb = i / 20, k = i % 20;
        const float* wr = dW + k * 128;
        const unsigned short* hr = lsH3p + bb * 128;
        float s = db[k];
        for (int jj = 0; jj < 128; ++jj) s += bf2f(hr[jj]) * wr[jj];
        lsOut[i] = s;
      }
    }
    __syncthreads();
    for (int i = tid; i < 2560; i += 256) {  // l3 gates, K = [out(20)|hl3(20)]
      int bb = i / 80, n = i % 80;
      const float* wr = W3 + n * 40;
      const float* ob = lsOut + bb * 20;
      const float* hp = hl3_in + (size_t)(rowbase1 + bb) * 20;
      float s = b3[n];
      for (int k = 0; k < 20; ++k) s += ob[k] * wr[k];
      for (int k = 0; k < 20; ++k) s += hp[k] * wr[20 + k];
      lsGates[i] = s;
    }
    __syncthreads();
    for (int i = tid; i < 640; i += 256) {  // l3 cell
      int bb = i / 20, jj = i % 20;
      const float* gg = lsGates + bb * 80;
      float iv = sigm(gg[jj]), fv = sigm(gg[20 + jj]);
      float gv = tanh_f(gg[40 + jj]), ov = sigm(gg[60 + jj]);
      float cc = fv * cl3_in[(size_t)(rowbase1 + bb) * 20 + jj] + iv * gv;
      float h = ov * tanh_f(cc);
      lsHnew[i] = h;
      if (c == 0) {
        hl3_out[(size_t)(rowbase1 + bb) * 20 + jj] = h;
        cl3_out[(size_t)(rowbase1 + bb) * 20 + jj] = cc;
      }
    }
    __syncthreads();
    // stage A: cols 0..19 = h_new (bf16), 20..23 = 0, 24..823 = h2_prev, 824.. = 0
    for (int i = tid; i < 3200; i += 256) {
      int bb = i / 100, ss = i % 100;
      *(uint4*)(ls + bb * 840 + 24 + ss * 8) =
          *(const uint4*)(h2_in + (size_t)(rowbase1 + bb) * 800 + ss * 8);
    }
    for (int i = tid; i < 640; i += 256) {
      int bb = i / 20, jj = i % 20;
      ls[bb * 840 + jj] = f2bf(lsHnew[i]);
    }
    for (int i = tid; i < 640; i += 256) {
      int bb = i / 20, z = i % 20;
      int col = (z < 4) ? (20 + z) : (820 + z);
      ls[bb * 840 + col] = 0;
    }
    __syncthreads();
    if (act1) {
      f32x4 acc[2][4];
#pragma unroll
      for (int mt = 0; mt < 2; ++mt)
#pragma unroll
        for (int gq = 0; gq < 4; ++gq) acc[mt][gq] = (f32x4){0.f, 0.f, 0.f, 0.f};
      for (int kc = 0; kc < 26; ++kc) {
        const int ko = kc * 32;
        bf16x8 a0 = *(const bf16x8*)(A0 + ko);
        bf16x8 a1 = *(const bf16x8*)(A1 + ko);
        bf16x8 bv0 = *(const bf16x8*)(Wp4 + (size_t)0 * 665600 + ko);
        bf16x8 bv1 = *(const bf16x8*)(Wp4 + (size_t)1 * 665600 + ko);
        bf16x8 bv2 = *(const bf16x8*)(Wp4 + (size_t)2 * 665600 + ko);
        bf16x8 bv3 = *(const bf16x8*)(Wp4 + (size_t)3 * 665600 + ko);
        acc[0][0] = __builtin_amdgcn_mfma_f32_16x16x32_bf16(a0, bv0, acc[0][0], 0, 0, 0);
        acc[1][0] = __builtin_amdgcn_mfma_f32_16x16x32_bf16(a1, bv0, acc[1][0], 0, 0, 0);
        acc[0][1] = __builtin_amdgcn_mfma_f32_16x16x32_bf16(a0, bv1, acc[0][1], 0, 0, 0);
        acc[1][1] = __builtin_amdgcn_mfma_f32_16x16x32_bf16(a1, bv1, acc[1][1], 0, 0, 0);
        acc[0][2] = __builtin_amdgcn_mfma_f32_16x16x32_bf16(a0, bv2, acc[0][2], 0, 0, 0);
        acc[1][2] = __builtin_amdgcn_mfma_f32_16x16x32_bf16(a1, bv2, acc[1][2], 0, 0, 0);
        acc[0][3] = __builtin_amdgcn_mfma_f32_16x16x32_bf16(a0, bv3, acc[0][3], 0, 0, 0);
        acc[1][3] = __builtin_amdgcn_mfma_f32_16x16x32_bf16(a1, bv3, acc[1][3], 0, 0, 0);
      }
#pragma unroll
      for (int mt = 0; mt < 2; ++mt) {
#pragma unroll
        for (int r = 0; r < 4; ++r) {
          int bg = rowbase1 + mt * 16 + quad * 4 + r;
          float iv = sigm(acc[mt][0][r] + bi4);
          float fv = sigm(acc[mt][1][r] + bf4);
          float gv = tanh_f(acc[mt][2][r] + bg4);
          float ov = sigm(acc[mt][3][r] + bo4);
          size_t ix = (size_t)bg * 800 + j4;
          float cc = fv * c2[ix] + iv * gv;
          c2[ix] = cc;
          h2_out[ix] = f2bf(ov * tanh_f(cc));
        }
      }
    }
    // ---- arrive A (own flag word, own cacheline; no RMW, no shared line) --
    __syncthreads();
    if (tid == 0) {
      __threadfence();
      __hip_atomic_store(&fA[c * 16], t + 1, __ATOMIC_RELEASE,
                         __HIP_MEMORY_SCOPE_AGENT);
    }

    // ================= phase 2 (c<4): wait A, l5 MFMA, arrive B ============
    if (act2) {
      if (tid < 13) {
        int guard = 0;
        while (__hip_atomic_load(&fA[tid * 16], __ATOMIC_ACQUIRE,
                                 __HIP_MEMORY_SCOPE_AGENT) < t + 1) {
          __builtin_amdgcn_s_sleep(2);
          if (++guard > SPIN_GUARD) break;
        }
      }
      __syncthreads();
      __threadfence();
      for (int i = tid; i < 3200; i += 256) {
        int bb = i / 100, ss = i % 100;
        *(uint4*)(ls + bb * 968 + ss * 8) =
            *(const uint4*)(h2_out + (size_t)(rowbase2 + bb) * 800 + ss * 8);
      }
      for (int i = tid; i < 512; i += 256) {
        int bb = i / 16, ss = i % 16;
        *(uint4*)(ls + bb * 968 + 800 + ss * 8) =
            *(const uint4*)(h3_in + (size_t)(rowbase2 + bb) * 128 + ss * 8);
      }
      for (int i = tid; i < 1280; i += 256) {
        int bb = i / 40, z = i % 40;
        ls[bb * 968 + 928 + z] = 0;
      }
      __syncthreads();
      f32x4 acc[4];
#pragma unroll
      for (int gq = 0; gq < 4; ++gq) acc[gq] = (f32x4){0.f, 0.f, 0.f, 0.f};
      for (int kc = 0; kc < 29; ++kc) {
        const int ko = kc * 32;
        bf16x8 a = *(const bf16x8*)(Ap5 + ko);
        bf16x8 bv0 = *(const bf16x8*)(Wp5 + (size_t)0 * 118784 + ko);
        bf16x8 bv1 = *(const bf16x8*)(Wp5 + (size_t)1 * 118784 + ko);
        bf16x8 bv2 = *(const bf16x8*)(Wp5 + (size_t)2 * 118784 + ko);
        bf16x8 bv3 = *(const bf16x8*)(Wp5 + (size_t)3 * 118784 + ko);
        acc[0] = __builtin_amdgcn_mfma_f32_16x16x32_bf16(a, bv0, acc[0], 0, 0, 0);
        acc[1] = __builtin_amdgcn_mfma_f32_16x16x32_bf16(a, bv1, acc[1], 0, 0, 0);
        acc[2] = __builtin_amdgcn_mfma_f32_16x16x32_bf16(a, bv2, acc[2], 0, 0, 0);
        acc[3] = __builtin_amdgcn_mfma_f32_16x16x32_bf16(a, bv3, acc[3], 0, 0, 0);
      }
#pragma unroll
      for (int r = 0; r < 4; ++r) {
        int bg = rowbase2 + mh * 16 + quad * 4 + r;
        float iv = sigm(acc[0][r] + bi5);
        float fv = sigm(acc[1][r] + bf5);
        float gv = tanh_f(acc[2][r] + bg5);
        float ov = sigm(acc[3][r] + bo5);
        size_t ix = (size_t)bg * 128 + j5;
        float cc = fv * c3[ix] + iv * gv;
        c3[ix] = cc;
        float h = ov * tanh_f(cc);
        dout[(size_t)t * 131072 + ix] = h;
        h3_out[ix] = f2bf(h);
      }
      __syncthreads();
      if (tid == 0) {
        __threadfence();
        __hip_atomic_store(&fB[c * 16], t + 1, __ATOMIC_RELEASE,
                           __HIP_MEMORY_SCOPE_AGENT);
      }
    }

    // ---- all blocks of the group wait for the 4 B-flags -------------------
    if (tid < 4) {
      int guard = 0;
      while (__hip_atomic_load(&fB[tid * 16], __ATOMIC_ACQUIRE,
                               __HIP_MEMORY_SCOPE_AGENT) < t + 1) {
        __builtin_amdgcn_s_sleep(2);
        if (++guard > SPIN_GUARD) break;
      }
    }
    __syncthreads();
    __threadfence();
  }
}

extern "C" void kernel_launch(void* const* d_in, const int* in_sizes, int n_in,
                              void* d_out, int out_size, void* d_ws, size_t ws_size,
                              hipStream_t stream) {
  (void)in_sizes; (void)n_in; (void)out_size; (void)ws_size;
  const float* x   = (const float*)d_in[0];
  const float* w1i = (const float*)d_in[1];
  const float* w1h = (const float*)d_in[2];
  const float* b1i = (const float*)d_in[3];
  const float* b1h = (const float*)d_in[4];
  const float* w2i = (const float*)d_in[5];
  const float* w2h = (const float*)d_in[6];
  const float* b2i = (const float*)d_in[7];
  const float* b2h = (const float*)d_in[8];
  const float* w3i = (const float*)d_in[9];
  const float* w3h = (const float*)d_in[10];
  const float* b3i = (const float*)d_in[11];
  const float* b3h = (const float*)d_in[12];
  const float* w4i = (const float*)d_in[13];
  const float* w4h = (const float*)d_in[14];
  const float* b4i = (const float*)d_in[15];
  const float* b4h = (const float*)d_in[16];
  const float* w5i = (const float*)d_in[17];
  const float* w5h = (const float*)d_in[18];
  const float* b5i = (const float*)d_in[19];
  const float* b5h = (const float*)d_in[20];
  const float* idW = (const float*)d_in[21];
  const float* idb = (const float*)d_in[22];
  const float* dW  = (const float*)d_in[23];
  const float* db  = (const float*)d_in[24];
  float* out = (float*)d_out;

  char* ws = (char*)d_ws;
  size_t off = 0;
  auto alloc = [&](size_t bytes) -> void* {
    void* p = ws + off;
    off = (off + bytes + 255) & ~(size_t)255;
    return p;
  };
  unsigned short* W4 = (unsigned short*)alloc(3200 * 832 * 2);
  unsigned short* W5 = (unsigned short*)alloc(512 * 928 * 2);
  float* W1 = (float*)alloc(240 * 192 * 4);
  float* W2 = (float*)alloc(80 * 80 * 4);
  float* W3 = (float*)alloc(80 * 40 * 4);
  float* b4 = (float*)alloc(3200 * 4);
  float* b5 = (float*)alloc(512 * 4);
  float* b1 = (float*)alloc(240 * 4);
  float* b2 = (float*)alloc(80 * 4);
  float* b3 = (float*)alloc(80 * 4);
  unsigned short* h2buf = (unsigned short*)alloc(2 * 1024 * 800 * 2);
  unsigned short* h3buf = (unsigned short*)alloc(2 * 1024 * 128 * 2);
  float* c2 = (float*)alloc(1024 * 800 * 4);
  float* c3 = (float*)alloc(1024 * 128 * 4);
  float* hl3 = (float*)alloc(2 * 1024 * 20 * 4);
  float* cl3 = (float*)alloc(2 * 1024 * 20 * 4);
  float* out0 = (float*)alloc(1024 * 20 * 4);
  int* flags = (int*)alloc(8704 * 4);   // 32 groups x 17 slots x 64B

  kPrep<<<dim3(4096), dim3(256), 0, stream>>>(
      w4i, w4h, b4i, b4h, w5i, w5h, b5i, b5h, w1i, w1h, b1i, b1h,
      w2i, w2h, b2i, b2h, w3i, w3h, b3i, b3h,
      W4, W5, W1, W2, W3, b4, b5, b1, b2, b3);
  kZero<<<dim3(2048), dim3(256), 0, stream>>>(c2, c3, (unsigned int*)h2buf,
                                              (unsigned int*)h3buf, flags);
  kEnc<<<dim3(256), dim3(256), 0, stream>>>(x, W1, b1, W2, b2, idW, idb,
                                            hl3, cl3, out0, out + 33554432);
  kDec<<<dim3(512), dim3(256), 0, stream>>>(
      W4, b4, W5, b5, W3, b3, dW, db, out0, hl3, cl3,
      h2buf, h3buf, c2, c3, out, flags);
}

// Round 5
// 31612.927 us; speedup vs baseline: 3.5057x; 2.8012x over previous
//
#include <hip/hip_runtime.h>
#include <stdint.h>

typedef __bf16 bf16x8 __attribute__((ext_vector_type(8)));
typedef float  f32x4  __attribute__((ext_vector_type(4)));

#define SPIN_GUARD (1 << 18)

static __device__ __forceinline__ unsigned short f2bf(float f) {
  unsigned int u = __float_as_uint(f);
  u = u + 0x7fffu + ((u >> 16) & 1u);
  return (unsigned short)(u >> 16);
}
static __device__ __forceinline__ float bf2f(unsigned short h) {
  return __uint_as_float(((unsigned int)h) << 16);
}
static __device__ __forceinline__ float sigm(float x) {
  return 1.f / (1.f + __expf(-x));
}
static __device__ __forceinline__ float tanh_f(float x) {
  float ax = fabsf(x);
  float e = __expf(-2.f * ax);
  float t = (1.f - e) / (1.f + e);
  return copysignf(t, x);
}

// Spin on RELAXED atomic loads (coherent at agent scope, but NO buffer_inv
// per poll), then ONE acquire load to publish producer writes to this CU.
// The acquire-per-poll variant invalidated the XCD L2 continuously and was
// the 97%-idle bottleneck of R2/R4 (FETCH_SIZE showed full weight refetch
// every step).
static __device__ __forceinline__ void waitFlag(const int* f, int target) {
  int guard = 0;
  while (__hip_atomic_load(f, __ATOMIC_RELAXED, __HIP_MEMORY_SCOPE_AGENT) < target) {
    __builtin_amdgcn_s_sleep(1);
    if (++guard > SPIN_GUARD) break;
  }
  (void)__hip_atomic_load(f, __ATOMIC_ACQUIRE, __HIP_MEMORY_SCOPE_AGENT);
}

// ---------------- weight packing (runs every launch; ws is re-poisoned) ----
__global__ void kPrep(const float* __restrict__ w4i, const float* __restrict__ w4h,
                      const float* __restrict__ b4i, const float* __restrict__ b4h,
                      const float* __restrict__ w5i, const float* __restrict__ w5h,
                      const float* __restrict__ b5i, const float* __restrict__ b5h,
                      const float* __restrict__ w1i, const float* __restrict__ w1h,
                      const float* __restrict__ b1i, const float* __restrict__ b1h,
                      const float* __restrict__ w2i, const float* __restrict__ w2h,
                      const float* __restrict__ b2i, const float* __restrict__ b2h,
                      const float* __restrict__ w3i, const float* __restrict__ w3h,
                      const float* __restrict__ b3i, const float* __restrict__ b3h,
                      unsigned short* __restrict__ W4, unsigned short* __restrict__ W5,
                      float* __restrict__ W1, float* __restrict__ W2, float* __restrict__ W3,
                      float* __restrict__ b4, float* __restrict__ b5,
                      float* __restrict__ b1, float* __restrict__ b2, float* __restrict__ b3) {
  int idx0 = blockIdx.x * blockDim.x + threadIdx.x;
  int stride = gridDim.x * blockDim.x;
  const int TOT = 3197328;
  for (int i = idx0; i < TOT; i += stride) {
    int i2 = i;
    if (i2 < 2662400) {
      int n = i2 / 832, k = i2 % 832;
      float v = (k < 20) ? w4i[n * 20 + k]
                         : ((k >= 24 && k < 824) ? w4h[n * 800 + (k - 24)] : 0.f);
      W4[i2] = f2bf(v);
      continue;
    }
    i2 -= 2662400;
    if (i2 < 475136) {
      int n = i2 / 928, k = i2 % 928;
      float v = (k < 800) ? w5i[n * 800 + k] : w5h[n * 128 + (k - 800)];
      W5[i2] = f2bf(v);
      continue;
    }
    i2 -= 475136;
    if (i2 < 46080) {
      int n = i2 / 192, k = i2 % 192;
      W1[i2] = (k < 128) ? w1i[n * 128 + k] : ((k < 188) ? w1h[n * 60 + (k - 128)] : 0.f);
      continue;
    }
    i2 -= 46080;
    if (i2 < 6400) {
      int n = i2 / 80, k = i2 % 80;
      W2[i2] = (k < 60) ? w2i[n * 60 + k] : w2h[n * 20 + (k - 60)];
      continue;
    }
    i2 -= 6400;
    if (i2 < 3200) {
      int n = i2 / 40, k = i2 % 40;
      W3[i2] = (k < 20) ? w3i[n * 20 + k] : w3h[n * 20 + (k - 20)];
      continue;
    }
    i2 -= 3200;
    if (i2 < 3200) { b4[i2] = b4i[i2] + b4h[i2]; continue; }
    i2 -= 3200;
    if (i2 < 512) { b5[i2] = b5i[i2] + b5h[i2]; continue; }
    i2 -= 512;
    if (i2 < 240) { b1[i2] = b1i[i2] + b1h[i2]; continue; }
    i2 -= 240;
    if (i2 < 80) { b2[i2] = b2i[i2] + b2h[i2]; continue; }
    i2 -= 80;
    b3[i2] = b3i[i2] + b3h[i2];
  }
}

__global__ void kZero(unsigned int* __restrict__ h2, unsigned int* __restrict__ h3,
                      int* __restrict__ flags) {
  int idx = blockIdx.x * blockDim.x + threadIdx.x;
  int stride = gridDim.x * blockDim.x;
  for (int i = idx; i < 409600; i += stride) h2[i] = 0u;
  for (int i = idx; i < 65536; i += stride) h3[i] = 0u;
  for (int i = idx; i < 8704; i += stride) flags[i] = 0;
}

// ---------------- encoder: fc1 + fc21 fused, 4 batch rows / block ----------
__global__ __launch_bounds__(256, 2)
void kEnc(const float* __restrict__ x,
          const float* __restrict__ W1, const float* __restrict__ b1,
          const float* __restrict__ W2, const float* __restrict__ b2,
          const float* __restrict__ idW, const float* __restrict__ idb,
          float* __restrict__ hl30, float* __restrict__ cl30,
          float* __restrict__ out0, float* __restrict__ muOut) {
  __shared__ float xb[512];
  __shared__ float hb[240], cbb[240], h1b[240];
  __shared__ float h21[80], c21[80];
  __shared__ float g1[960], g2[320];
  const int tid = threadIdx.x;
  const int rowbase = blockIdx.x * 4;
  if (tid < 240) { hb[tid] = 0.f; cbb[tid] = 0.f; h1b[tid] = 0.f; }
  if (tid < 80) { h21[tid] = 0.f; c21[tid] = 0.f; }
  __syncthreads();
  for (int t = 0; t < 256; ++t) {
    const float* xs = x + ((size_t)t * 1024 + rowbase) * 128;
    xb[tid] = xs[tid];
    xb[tid + 256] = xs[tid + 256];
    __syncthreads();
    if (tid < 240) {
      const float* wr = W1 + tid * 192;
      float s0 = b1[tid], s1 = s0, s2 = s0, s3 = s0;
      for (int k = 0; k < 128; ++k) {
        float w = wr[k];
        s0 += w * xb[k]; s1 += w * xb[128 + k]; s2 += w * xb[256 + k]; s3 += w * xb[384 + k];
      }
      for (int k = 0; k < 60; ++k) {
        float w = wr[128 + k];
        s0 += w * hb[k]; s1 += w * hb[60 + k]; s2 += w * hb[120 + k]; s3 += w * hb[180 + k];
      }
      g1[tid] = s0; g1[240 + tid] = s1; g1[480 + tid] = s2; g1[720 + tid] = s3;
    }
    __syncthreads();
    if (tid < 240) {
      int b = tid / 60, j = tid % 60;
      const float* g = g1 + b * 240;
      float iv = sigm(g[j]), fv = sigm(g[60 + j]), gv = tanh_f(g[120 + j]), ov = sigm(g[180 + j]);
      float c = fv * cbb[b * 60 + j] + iv * gv;
      cbb[b * 60 + j] = c;
      float h = ov * tanh_f(c);
      hb[b * 60 + j] = h;
      h1b[b * 60 + j] = fmaxf(h, 0.f);
    }
    __syncthreads();
    if (tid < 80) {
      const float* wr = W2 + tid * 80;
      float s0 = b2[tid], s1 = s0, s2 = s0, s3 = s0;
      for (int k = 0; k < 60; ++k) {
        float w = wr[k];
        s0 += w * h1b[k]; s1 += w * h1b[60 + k]; s2 += w * h1b[120 + k]; s3 += w * h1b[180 + k];
      }
      for (int k = 0; k < 20; ++k) {
        float w = wr[60 + k];
        s0 += w * h21[k]; s1 += w * h21[20 + k]; s2 += w * h21[40 + k]; s3 += w * h21[60 + k];
      }
      g2[tid] = s0; g2[80 + tid] = s1; g2[160 + tid] = s2; g2[240 + tid] = s3;
    }
    __syncthreads();
    if (tid < 80) {
      int b = tid / 20, j = tid % 20;
      const float* g = g2 + b * 80;
      float iv = sigm(g[j]), fv = sigm(g[20 + j]), gv = tanh_f(g[40 + j]), ov = sigm(g[60 + j]);
      float c = fv * c21[b * 20 + j] + iv * gv;
      c21[b * 20 + j] = c;
      h21[b * 20 + j] = ov * tanh_f(c);
    }
    __syncthreads();
  }
  if (tid < 80) {
    int b = tid / 20, j = tid % 20;
    int gb = rowbase + b;
    float mu = h21[b * 20 + j];
    muOut[(size_t)gb * 20 + j] = mu;
    hl30[gb * 20 + j] = mu;
    cl30[gb * 20 + j] = c21[b * 20 + j];
    float s = idb[j];
    for (int k = 0; k < 20; ++k) s += h21[b * 20 + k] * idW[j * 20 + k];
    out0[gb * 20 + j] = s;
  }
}

// ---------------- persistent decoder: per-row-group flag sync --------------
// grid = 512 blocks (32 row-groups x 16 slots; slots 13..15 exit). Block
// (g, c): phase 1 = l4 col-tile c (64 cols) for rows g*32..+31. Blocks c<4
// additionally run phase 2 (l5, 32 h3-cols each). Per-group flags; RELAXED
// spin + single acquire (see waitFlag). c2/c3 LSTM cell state lives in
// REGISTERS (block-exclusive across all 256 steps). 512 blocks x 62KB LDS
// = 2/CU, all resident.
__global__ __launch_bounds__(256, 2)
void kDec(const unsigned short* __restrict__ W4, const float* __restrict__ b4,
          const unsigned short* __restrict__ W5, const float* __restrict__ b5,
          const float* __restrict__ W3, const float* __restrict__ b3,
          const float* __restrict__ dW, const float* __restrict__ db,
          const float* __restrict__ out0,
          float* __restrict__ hl3buf, float* __restrict__ cl3buf,
          unsigned short* __restrict__ h2buf, unsigned short* __restrict__ h3buf,
          float* __restrict__ dout, int* flags) {
  const int blk = blockIdx.x;
  const int g = blk >> 4;      // row-group 0..31
  const int c = blk & 15;      // col-slot 0..15
  if (c >= 13) return;         // ghost slot (XCD-pinning pad)

  __shared__ __align__(16) unsigned short ls[32 * 968];  // 61952 B, both phases
  float* lsOut = (float*)ls;                   // 640 f32   (bytes 0..2560)
  float* lsGates = (float*)(ls + 1280);        // 2560 f32  (bytes 2560..12800)
  unsigned short* lsH3p = ls + 6400;           // 4096 u16  (bytes 12800..20992)
  float* lsHnew = (float*)(ls + 26880);        // 640 f32   (bytes 53760..56320)

  const int tid = threadIdx.x;
  const int rowbase1 = g * 32;
  const int cb = c * 64;
  const int ncols = (cb + 64 <= 800) ? 64 : (800 - cb);
  const int w = tid >> 6, lane = tid & 63, quad = lane >> 4, l16 = lane & 15;

  // ---- loop-invariant phase-1 addressing ----
  const int jwl = w * 16;
  const bool act1 = (jwl < ncols);
  const int j4 = cb + jwl + l16;
  const unsigned short* Wp4 = W4 + (size_t)j4 * 832 + quad * 8;
  const unsigned short* A0 = ls + l16 * 840 + quad * 8;
  const unsigned short* A1 = ls + (16 + l16) * 840 + quad * 8;
  float bi4 = 0.f, bf4 = 0.f, bg4 = 0.f, bo4 = 0.f;
  if (act1) { bi4 = b4[j4]; bf4 = b4[800 + j4]; bg4 = b4[1600 + j4]; bo4 = b4[2400 + j4]; }
  float creg2[8];
#pragma unroll
  for (int i = 0; i < 8; ++i) creg2[i] = 0.f;

  // ---- loop-invariant phase-2 addressing (blocks c<4 of each group) ----
  const bool act2 = (c < 4);
  const int rowbase2 = rowbase1;
  const int colbase2 = c * 32;
  const int mh = w >> 1, jh = w & 1;
  const int j5 = colbase2 + jh * 16 + l16;
  const unsigned short* Wp5 = W5 + (size_t)j5 * 928 + quad * 8;
  const unsigned short* Ap5 = ls + (mh * 16 + l16) * 968 + quad * 8;
  float bi5 = 0.f, bf5 = 0.f, bg5 = 0.f, bo5 = 0.f;
  if (act2) { bi5 = b5[j5]; bf5 = b5[128 + j5]; bg5 = b5[256 + j5]; bo5 = b5[384 + j5]; }
  float creg3[4];
#pragma unroll
  for (int i = 0; i < 4; ++i) creg3[i] = 0.f;

  int* fA = flags + (size_t)(g * 17) * 16;        // 13 A-flags, 64B apart
  int* fB = flags + (size_t)(g * 17 + 13) * 16;   // 4 B-flags, 64B apart

  for (int t = 0; t < 256; ++t) {
    const int p = t & 1;
    const unsigned short* h2_in = h2buf + (size_t)p * 819200;
    unsigned short* h2_out = h2buf + (size_t)(1 - p) * 819200;
    const unsigned short* h3_in = h3buf + (size_t)p * 131072;
    unsigned short* h3_out = h3buf + (size_t)(1 - p) * 131072;
    const float* hl3_in = hl3buf + (size_t)p * 20480;
    float* hl3_out = hl3buf + (size_t)(1 - p) * 20480;
    const float* cl3_in = cl3buf + (size_t)p * 20480;
    float* cl3_out = cl3buf + (size_t)(1 - p) * 20480;

    // ================= phase 1: down + l3 (scalar) + l4 (MFMA) =============
    if (t > 0) {  // stage h3_prev tile (32x128 bf16, contiguous)
      const uint4* src = (const uint4*)(h3_in + (size_t)rowbase1 * 128);
      uint4* dst = (uint4*)lsH3p;
      for (int i = tid; i < 512; i += 256) dst[i] = src[i];
    }
    __syncthreads();
    if (t == 0) {
      for (int i = tid; i < 640; i += 256) {
        int bb = i / 20, k = i % 20;
        lsOut[i] = out0[(size_t)(rowbase1 + bb) * 20 + k];
      }
    } else {  // out = h3_prev @ dW^T + db
      for (int i = tid; i < 640; i += 256) {
        int bb = i / 20, k = i % 20;
        const float* wr = dW + k * 128;
        const unsigned short* hr = lsH3p + bb * 128;
        float s = db[k];
        for (int jj = 0; jj < 128; ++jj) s += bf2f(hr[jj]) * wr[jj];
        lsOut[i] = s;
      }
    }
    __syncthreads();
    for (int i = tid; i < 2560; i += 256) {  // l3 gates, K = [out(20)|hl3(20)]
      int bb = i / 80, n = i % 80;
      const float* wr = W3 + n * 40;
      const float* ob = lsOut + bb * 20;
      const float* hp = hl3_in + (size_t)(rowbase1 + bb) * 20;
      float s = b3[n];
      for (int k = 0; k < 20; ++k) s += ob[k] * wr[k];
      for (int k = 0; k < 20; ++k) s += hp[k] * wr[20 + k];
      lsGates[i] = s;
    }
    __syncthreads();
    for (int i = tid; i < 640; i += 256) {  // l3 cell
      int bb = i / 20, jj = i % 20;
      const float* gg = lsGates + bb * 80;
      float iv = sigm(gg[jj]), fv = sigm(gg[20 + jj]);
      float gv = tanh_f(gg[40 + jj]), ov = sigm(gg[60 + jj]);
      float cc = fv * cl3_in[(size_t)(rowbase1 + bb) * 20 + jj] + iv * gv;
      float h = ov * tanh_f(cc);
      lsHnew[i] = h;
      if (c == 0) {
        hl3_out[(size_t)(rowbase1 + bb) * 20 + jj] = h;
        cl3_out[(size_t)(rowbase1 + bb) * 20 + jj] = cc;
      }
    }
    __syncthreads();
    // stage A: cols 0..19 = h_new (bf16), 20..23 = 0, 24..823 = h2_prev, 824.. = 0
    for (int i = tid; i < 3200; i += 256) {
      int bb = i / 100, ss = i % 100;
      *(uint4*)(ls + bb * 840 + 24 + ss * 8) =
          *(const uint4*)(h2_in + (size_t)(rowbase1 + bb) * 800 + ss * 8);
    }
    for (int i = tid; i < 640; i += 256) {
      int bb = i / 20, jj = i % 20;
      ls[bb * 840 + jj] = f2bf(lsHnew[i]);
    }
    for (int i = tid; i < 640; i += 256) {
      int bb = i / 20, z = i % 20;
      int col = (z < 4) ? (20 + z) : (820 + z);
      ls[bb * 840 + col] = 0;
    }
    __syncthreads();
    if (act1) {
      f32x4 acc[2][4];
#pragma unroll
      for (int mt = 0; mt < 2; ++mt)
#pragma unroll
        for (int gq = 0; gq < 4; ++gq) acc[mt][gq] = (f32x4){0.f, 0.f, 0.f, 0.f};
      for (int kc = 0; kc < 26; ++kc) {
        const int ko = kc * 32;
        bf16x8 a0 = *(const bf16x8*)(A0 + ko);
        bf16x8 a1 = *(const bf16x8*)(A1 + ko);
        bf16x8 bv0 = *(const bf16x8*)(Wp4 + (size_t)0 * 665600 + ko);
        bf16x8 bv1 = *(const bf16x8*)(Wp4 + (size_t)1 * 665600 + ko);
        bf16x8 bv2 = *(const bf16x8*)(Wp4 + (size_t)2 * 665600 + ko);
        bf16x8 bv3 = *(const bf16x8*)(Wp4 + (size_t)3 * 665600 + ko);
        acc[0][0] = __builtin_amdgcn_mfma_f32_16x16x32_bf16(a0, bv0, acc[0][0], 0, 0, 0);
        acc[1][0] = __builtin_amdgcn_mfma_f32_16x16x32_bf16(a1, bv0, acc[1][0], 0, 0, 0);
        acc[0][1] = __builtin_amdgcn_mfma_f32_16x16x32_bf16(a0, bv1, acc[0][1], 0, 0, 0);
        acc[1][1] = __builtin_amdgcn_mfma_f32_16x16x32_bf16(a1, bv1, acc[1][1], 0, 0, 0);
        acc[0][2] = __builtin_amdgcn_mfma_f32_16x16x32_bf16(a0, bv2, acc[0][2], 0, 0, 0);
        acc[1][2] = __builtin_amdgcn_mfma_f32_16x16x32_bf16(a1, bv2, acc[1][2], 0, 0, 0);
        acc[0][3] = __builtin_amdgcn_mfma_f32_16x16x32_bf16(a0, bv3, acc[0][3], 0, 0, 0);
        acc[1][3] = __builtin_amdgcn_mfma_f32_16x16x32_bf16(a1, bv3, acc[1][3], 0, 0, 0);
      }
#pragma unroll
      for (int mt = 0; mt < 2; ++mt) {
#pragma unroll
        for (int r = 0; r < 4; ++r) {
          int bg = rowbase1 + mt * 16 + quad * 4 + r;
          float iv = sigm(acc[mt][0][r] + bi4);
          float fv = sigm(acc[mt][1][r] + bf4);
          float gv = tanh_f(acc[mt][2][r] + bg4);
          float ov = sigm(acc[mt][3][r] + bo4);
          float cc = fv * creg2[mt * 4 + r] + iv * gv;
          creg2[mt * 4 + r] = cc;
          h2_out[(size_t)bg * 800 + j4] = f2bf(ov * tanh_f(cc));
        }
      }
    }
    // ---- arrive A (own flag word, own cacheline; release store only) ------
    __syncthreads();
    if (tid == 0) {
      __hip_atomic_store(&fA[c * 16], t + 1, __ATOMIC_RELEASE,
                         __HIP_MEMORY_SCOPE_AGENT);
    }

    // ================= phase 2 (c<4): wait A, l5 MFMA, arrive B ============
    if (act2) {
      if (tid < 13) waitFlag(&fA[tid * 16], t + 1);
      __syncthreads();
      for (int i = tid; i < 3200; i += 256) {
        int bb = i / 100, ss = i % 100;
        *(uint4*)(ls + bb * 968 + ss * 8) =
            *(const uint4*)(h2_out + (size_t)(rowbase2 + bb) * 800 + ss * 8);
      }
      for (int i = tid; i < 512; i += 256) {
        int bb = i / 16, ss = i % 16;
        *(uint4*)(ls + bb * 968 + 800 + ss * 8) =
            *(const uint4*)(h3_in + (size_t)(rowbase2 + bb) * 128 + ss * 8);
      }
      for (int i = tid; i < 1280; i += 256) {
        int bb = i / 40, z = i % 40;
        ls[bb * 968 + 928 + z] = 0;
      }
      __syncthreads();
      f32x4 acc[4];
#pragma unroll
      for (int gq = 0; gq < 4; ++gq) acc[gq] = (f32x4){0.f, 0.f, 0.f, 0.f};
      for (int kc = 0; kc < 29; ++kc) {
        const int ko = kc * 32;
        bf16x8 a = *(const bf16x8*)(Ap5 + ko);
        bf16x8 bv0 = *(const bf16x8*)(Wp5 + (size_t)0 * 118784 + ko);
        bf16x8 bv1 = *(const bf16x8*)(Wp5 + (size_t)1 * 118784 + ko);
        bf16x8 bv2 = *(const bf16x8*)(Wp5 + (size_t)2 * 118784 + ko);
        bf16x8 bv3 = *(const bf16x8*)(Wp5 + (size_t)3 * 118784 + ko);
        acc[0] = __builtin_amdgcn_mfma_f32_16x16x32_bf16(a, bv0, acc[0], 0, 0, 0);
        acc[1] = __builtin_amdgcn_mfma_f32_16x16x32_bf16(a, bv1, acc[1], 0, 0, 0);
        acc[2] = __builtin_amdgcn_mfma_f32_16x16x32_bf16(a, bv2, acc[2], 0, 0, 0);
        acc[3] = __builtin_amdgcn_mfma_f32_16x16x32_bf16(a, bv3, acc[3], 0, 0, 0);
      }
#pragma unroll
      for (int r = 0; r < 4; ++r) {
        int bg = rowbase2 + mh * 16 + quad * 4 + r;
        float iv = sigm(acc[0][r] + bi5);
        float fv = sigm(acc[1][r] + bf5);
        float gv = tanh_f(acc[2][r] + bg5);
        float ov = sigm(acc[3][r] + bo5);
        float cc = fv * creg3[r] + iv * gv;
        creg3[r] = cc;
        float h = ov * tanh_f(cc);
        size_t ix = (size_t)bg * 128 + j5;
        dout[(size_t)t * 131072 + ix] = h;
        h3_out[ix] = f2bf(h);
      }
      __syncthreads();
      if (tid == 0) {
        __hip_atomic_store(&fB[c * 16], t + 1, __ATOMIC_RELEASE,
                           __HIP_MEMORY_SCOPE_AGENT);
      }
    }

    // ---- all blocks of the group wait for the 4 B-flags -------------------
    if (tid < 4) waitFlag(&fB[tid * 16], t + 1);
    __syncthreads();
  }
}

extern "C" void kernel_launch(void* const* d_in, const int* in_sizes, int n_in,
                              void* d_out, int out_size, void* d_ws, size_t ws_size,
                              hipStream_t stream) {
  (void)in_sizes; (void)n_in; (void)out_size; (void)ws_size;
  const float* x   = (const float*)d_in[0];
  const float* w1i = (const float*)d_in[1];
  const float* w1h = (const float*)d_in[2];
  const float* b1i = (const float*)d_in[3];
  const float* b1h = (const float*)d_in[4];
  const float* w2i = (const float*)d_in[5];
  const float* w2h = (const float*)d_in[6];
  const float* b2i = (const float*)d_in[7];
  const float* b2h = (const float*)d_in[8];
  const float* w3i = (const float*)d_in[9];
  const float* w3h = (const float*)d_in[10];
  const float* b3i = (const float*)d_in[11];
  const float* b3h = (const float*)d_in[12];
  const float* w4i = (const float*)d_in[13];
  const float* w4h = (const float*)d_in[14];
  const float* b4i = (const float*)d_in[15];
  const float* b4h = (const float*)d_in[16];
  const float* w5i = (const float*)d_in[17];
  const float* w5h = (const float*)d_in[18];
  const float* b5i = (const float*)d_in[19];
  const float* b5h = (const float*)d_in[20];
  const float* idW = (const float*)d_in[21];
  const float* idb = (const float*)d_in[22];
  const float* dW  = (const float*)d_in[23];
  const float* db  = (const float*)d_in[24];
  float* out = (float*)d_out;

  char* ws = (char*)d_ws;
  size_t off = 0;
  auto alloc = [&](size_t bytes) -> void* {
    void* p = ws + off;
    off = (off + bytes + 255) & ~(size_t)255;
    return p;
  };
  unsigned short* W4 = (unsigned short*)alloc(3200 * 832 * 2);
  unsigned short* W5 = (unsigned short*)alloc(512 * 928 * 2);
  float* W1 = (float*)alloc(240 * 192 * 4);
  float* W2 = (float*)alloc(80 * 80 * 4);
  float* W3 = (float*)alloc(80 * 40 * 4);
  float* b4 = (float*)alloc(3200 * 4);
  float* b5 = (float*)alloc(512 * 4);
  float* b1 = (float*)alloc(240 * 4);
  float* b2 = (float*)alloc(80 * 4);
  float* b3 = (float*)alloc(80 * 4);
  unsigned short* h2buf = (unsigned short*)alloc(2 * 1024 * 800 * 2);
  unsigned short* h3buf = (unsigned short*)alloc(2 * 1024 * 128 * 2);
  float* hl3 = (float*)alloc(2 * 1024 * 20 * 4);
  float* cl3 = (float*)alloc(2 * 1024 * 20 * 4);
  float* out0 = (float*)alloc(1024 * 20 * 4);
  int* flags = (int*)alloc(8704 * 4);   // 32 groups x 17 slots x 64B

  kPrep<<<dim3(4096), dim3(256), 0, stream>>>(
      w4i, w4h, b4i, b4h, w5i, w5h, b5i, b5h, w1i, w1h, b1i, b1h,
      w2i, w2h, b2i, b2h, w3i, w3h, b3i, b3h,
      W4, W5, W1, W2, W3, b4, b5, b1, b2, b3);
  kZero<<<dim3(2048), dim3(256), 0, stream>>>((unsigned int*)h2buf,
                                              (unsigned int*)h3buf, flags);
  kEnc<<<dim3(256), dim3(256), 0, stream>>>(x, W1, b1, W2, b2, idW, idb,
                                            hl3, cl3, out0, out + 33554432);
  kDec<<<dim3(512), dim3(256), 0, stream>>>(
      W4, b4, W5, b5, W3, b3, dW, db, out0, hl3, cl3,
      h2buf, h3buf, out, flags);
}

// Round 6
// 30151.224 us; speedup vs baseline: 3.6757x; 1.0485x over previous
//
#include <hip/hip_runtime.h>
#include <stdint.h>

typedef __bf16 bf16x8 __attribute__((ext_vector_type(8)));
typedef float  f32x4  __attribute__((ext_vector_type(4)));

#define SPIN_GUARD (1 << 18)

static __device__ __forceinline__ unsigned short f2bf(float f) {
  unsigned int u = __float_as_uint(f);
  u = u + 0x7fffu + ((u >> 16) & 1u);
  return (unsigned short)(u >> 16);
}
static __device__ __forceinline__ float bf2f(unsigned short h) {
  return __uint_as_float(((unsigned int)h) << 16);
}
static __device__ __forceinline__ float sigm(float x) {
  return 1.f / (1.f + __expf(-x));
}
static __device__ __forceinline__ float tanh_f(float x) {
  float ax = fabsf(x);
  float e = __expf(-2.f * ax);
  float t = (1.f - e) / (1.f + e);
  return copysignf(t, x);
}

// Line-granular coherent accessors: agent-scope RELAXED atomics go to the LLC
// (coherence point) per-access with NO buffer_inv / buffer_wbl2. This is the
// fix for R4/R5: acquire/release cache-wide ops were invalidating each XCD's
// L2 ~100x/step, forcing full weight refetch (FETCH_SIZE 54MB/step).
static __device__ __forceinline__ unsigned long long ldc8(const unsigned long long* p) {
  return __hip_atomic_load(p, __ATOMIC_RELAXED, __HIP_MEMORY_SCOPE_AGENT);
}
static __device__ __forceinline__ void stc8(unsigned long long* p, unsigned long long v) {
  __hip_atomic_store(p, v, __ATOMIC_RELAXED, __HIP_MEMORY_SCOPE_AGENT);
}
static __device__ __forceinline__ float ldc4f(const float* p) {
  return __hip_atomic_load(p, __ATOMIC_RELAXED, __HIP_MEMORY_SCOPE_AGENT);
}

static __device__ __forceinline__ void waitFlag(const int* f, int target) {
  int guard = 0;
  while (__hip_atomic_load(f, __ATOMIC_RELAXED, __HIP_MEMORY_SCOPE_AGENT) < target) {
    __builtin_amdgcn_s_sleep(1);
    if (++guard > SPIN_GUARD) break;
  }
  asm volatile("" ::: "memory");
}

// ---------------- weight packing (runs every launch; ws is re-poisoned) ----
__global__ void kPrep(const float* __restrict__ w4i, const float* __restrict__ w4h,
                      const float* __restrict__ b4i, const float* __restrict__ b4h,
                      const float* __restrict__ w5i, const float* __restrict__ w5h,
                      const float* __restrict__ b5i, const float* __restrict__ b5h,
                      const float* __restrict__ w1i, const float* __restrict__ w1h,
                      const float* __restrict__ b1i, const float* __restrict__ b1h,
                      const float* __restrict__ w2i, const float* __restrict__ w2h,
                      const float* __restrict__ b2i, const float* __restrict__ b2h,
                      const float* __restrict__ w3i, const float* __restrict__ w3h,
                      const float* __restrict__ b3i, const float* __restrict__ b3h,
                      unsigned short* __restrict__ W4, unsigned short* __restrict__ W5,
                      float* __restrict__ W1, float* __restrict__ W2, float* __restrict__ W3,
                      float* __restrict__ b4, float* __restrict__ b5,
                      float* __restrict__ b1, float* __restrict__ b2, float* __restrict__ b3) {
  int idx0 = blockIdx.x * blockDim.x + threadIdx.x;
  int stride = gridDim.x * blockDim.x;
  const int TOT = 3197328;
  for (int i = idx0; i < TOT; i += stride) {
    int i2 = i;
    if (i2 < 2662400) {
      int n = i2 / 832, k = i2 % 832;
      float v = (k < 20) ? w4i[n * 20 + k]
                         : ((k >= 24 && k < 824) ? w4h[n * 800 + (k - 24)] : 0.f);
      W4[i2] = f2bf(v);
      continue;
    }
    i2 -= 2662400;
    if (i2 < 475136) {
      int n = i2 / 928, k = i2 % 928;
      float v = (k < 800) ? w5i[n * 800 + k] : w5h[n * 128 + (k - 800)];
      W5[i2] = f2bf(v);
      continue;
    }
    i2 -= 475136;
    if (i2 < 46080) {
      int n = i2 / 192, k = i2 % 192;
      W1[i2] = (k < 128) ? w1i[n * 128 + k] : ((k < 188) ? w1h[n * 60 + (k - 128)] : 0.f);
      continue;
    }
    i2 -= 46080;
    if (i2 < 6400) {
      int n = i2 / 80, k = i2 % 80;
      W2[i2] = (k < 60) ? w2i[n * 60 + k] : w2h[n * 20 + (k - 60)];
      continue;
    }
    i2 -= 6400;
    if (i2 < 3200) {
      int n = i2 / 40, k = i2 % 40;
      W3[i2] = (k < 20) ? w3i[n * 20 + k] : w3h[n * 20 + (k - 20)];
      continue;
    }
    i2 -= 3200;
    if (i2 < 3200) { b4[i2] = b4i[i2] + b4h[i2]; continue; }
    i2 -= 3200;
    if (i2 < 512) { b5[i2] = b5i[i2] + b5h[i2]; continue; }
    i2 -= 512;
    if (i2 < 240) { b1[i2] = b1i[i2] + b1h[i2]; continue; }
    i2 -= 240;
    if (i2 < 80) { b2[i2] = b2i[i2] + b2h[i2]; continue; }
    i2 -= 80;
    b3[i2] = b3i[i2] + b3h[i2];
  }
}

__global__ void kZero(unsigned int* __restrict__ h2, unsigned int* __restrict__ h3,
                      int* __restrict__ flags) {
  int idx = blockIdx.x * blockDim.x + threadIdx.x;
  int stride = gridDim.x * blockDim.x;
  for (int i = idx; i < 409600; i += stride) h2[i] = 0u;
  for (int i = idx; i < 65536; i += stride) h3[i] = 0u;
  for (int i = idx; i < 8704; i += stride) flags[i] = 0;
}

// ---------------- encoder: fc1 + fc21 fused, 4 batch rows / block ----------
__global__ __launch_bounds__(256, 2)
void kEnc(const float* __restrict__ x,
          const float* __restrict__ W1, const float* __restrict__ b1,
          const float* __restrict__ W2, const float* __restrict__ b2,
          const float* __restrict__ idW, const float* __restrict__ idb,
          float* __restrict__ hl30, float* __restrict__ cl30,
          float* __restrict__ out0, float* __restrict__ muOut) {
  __shared__ float xb[512];
  __shared__ float hb[240], cbb[240], h1b[240];
  __shared__ float h21[80], c21[80];
  __shared__ float g1[960], g2[320];
  const int tid = threadIdx.x;
  const int rowbase = blockIdx.x * 4;
  if (tid < 240) { hb[tid] = 0.f; cbb[tid] = 0.f; h1b[tid] = 0.f; }
  if (tid < 80) { h21[tid] = 0.f; c21[tid] = 0.f; }
  __syncthreads();
  for (int t = 0; t < 256; ++t) {
    const float* xs = x + ((size_t)t * 1024 + rowbase) * 128;
    xb[tid] = xs[tid];
    xb[tid + 256] = xs[tid + 256];
    __syncthreads();
    if (tid < 240) {
      const float* wr = W1 + tid * 192;
      float s0 = b1[tid], s1 = s0, s2 = s0, s3 = s0;
      for (int k = 0; k < 128; ++k) {
        float w = wr[k];
        s0 += w * xb[k]; s1 += w * xb[128 + k]; s2 += w * xb[256 + k]; s3 += w * xb[384 + k];
      }
      for (int k = 0; k < 60; ++k) {
        float w = wr[128 + k];
        s0 += w * hb[k]; s1 += w * hb[60 + k]; s2 += w * hb[120 + k]; s3 += w * hb[180 + k];
      }
      g1[tid] = s0; g1[240 + tid] = s1; g1[480 + tid] = s2; g1[720 + tid] = s3;
    }
    __syncthreads();
    if (tid < 240) {
      int b = tid / 60, j = tid % 60;
      const float* g = g1 + b * 240;
      float iv = sigm(g[j]), fv = sigm(g[60 + j]), gv = tanh_f(g[120 + j]), ov = sigm(g[180 + j]);
      float c = fv * cbb[b * 60 + j] + iv * gv;
      cbb[b * 60 + j] = c;
      float h = ov * tanh_f(c);
      hb[b * 60 + j] = h;
      h1b[b * 60 + j] = fmaxf(h, 0.f);
    }
    __syncthreads();
    if (tid < 80) {
      const float* wr = W2 + tid * 80;
      float s0 = b2[tid], s1 = s0, s2 = s0, s3 = s0;
      for (int k = 0; k < 60; ++k) {
        float w = wr[k];
        s0 += w * h1b[k]; s1 += w * h1b[60 + k]; s2 += w * h1b[120 + k]; s3 += w * h1b[180 + k];
      }
      for (int k = 0; k < 20; ++k) {
        float w = wr[60 + k];
        s0 += w * h21[k]; s1 += w * h21[20 + k]; s2 += w * h21[40 + k]; s3 += w * h21[60 + k];
      }
      g2[tid] = s0; g2[80 + tid] = s1; g2[160 + tid] = s2; g2[240 + tid] = s3;
    }
    __syncthreads();
    if (tid < 80) {
      int b = tid / 20, j = tid % 20;
      const float* g = g2 + b * 80;
      float iv = sigm(g[j]), fv = sigm(g[20 + j]), gv = tanh_f(g[40 + j]), ov = sigm(g[60 + j]);
      float c = fv * c21[b * 20 + j] + iv * gv;
      c21[b * 20 + j] = c;
      h21[b * 20 + j] = ov * tanh_f(c);
    }
    __syncthreads();
  }
  if (tid < 80) {
    int b = tid / 20, j = tid % 20;
    int gb = rowbase + b;
    float mu = h21[b * 20 + j];
    muOut[(size_t)gb * 20 + j] = mu;
    hl30[gb * 20 + j] = mu;
    cl30[gb * 20 + j] = c21[b * 20 + j];
    float s = idb[j];
    for (int k = 0; k < 20; ++k) s += h21[b * 20 + k] * idW[j * 20 + k];
    out0[gb * 20 + j] = s;
  }
}

// ---------------- persistent decoder -------------------------------------
// grid = 416 blocks, c-MAJOR: c = blk>>5 (col-tile 0..12), g = blk&31
// (row-group). Chunked dispatch then gives each XCD ~1.6 col-tiles -> W4
// slice ~0.8MB stays L2-resident (weights read with PLAIN cached loads; no
// cache-wide inv anywhere). All cross-block activation traffic (h2, h3) via
// 8B agent-relaxed atomics (LLC-coherent, line-granular). l3 state hl3/cl3
// is block-local persistent LDS (every block recomputes l3 redundantly).
// ph2 (l5) tile q of group g is owned by block c == (g+3q)%13 (spreads l5
// across XCDs). LDS 65024B -> 2 blocks/CU, 416 blocks all resident.
__global__ __launch_bounds__(256, 2)
void kDec(const unsigned short* __restrict__ W4, const float* __restrict__ b4,
          const unsigned short* __restrict__ W5, const float* __restrict__ b5,
          const float* __restrict__ W3, const float* __restrict__ b3,
          const float* __restrict__ dW, const float* __restrict__ db,
          const float* __restrict__ out0,
          const float* __restrict__ hl30, const float* __restrict__ cl30,
          unsigned short* __restrict__ h2buf, unsigned short* __restrict__ h3buf,
          float* __restrict__ dout, int* flags) {
  const int blk = blockIdx.x;
  const int c = blk >> 5;      // col-tile 0..12
  const int g = blk & 31;      // row-group 0..31

  __shared__ __align__(16) unsigned short ls[32 * 936];  // 59904 B
  __shared__ float hl3p[640], cl3p[640];                 // persistent l3 state
  float* lsOut = (float*)ls;                   // 640 f32
  float* lsGates = (float*)(ls + 1280);        // 2560 f32
  unsigned short* lsH3p = ls + 6400;           // 4096 u16

  const int tid = threadIdx.x;
  const int rowbase1 = g * 32;
  const int cb = c * 64;
  const int ncols = (cb + 64 <= 800) ? 64 : (800 - cb);
  const int w = tid >> 6, lane = tid & 63, quad = lane >> 4, l16 = lane & 15;

  // ---- phase-1 loop invariants ----
  const int jwl = w * 16;
  const bool act1 = (jwl < ncols);
  const int j4 = cb + jwl + l16;
  const unsigned short* Wp4 = W4 + (size_t)j4 * 832 + quad * 8;
  const unsigned short* A0 = ls + l16 * 840 + quad * 8;
  const unsigned short* A1 = ls + (16 + l16) * 840 + quad * 8;
  float bi4 = 0.f, bf4 = 0.f, bg4 = 0.f, bo4 = 0.f;
  if (act1) { bi4 = b4[j4]; bf4 = b4[800 + j4]; bg4 = b4[1600 + j4]; bo4 = b4[2400 + j4]; }
  float creg2[8];
#pragma unroll
  for (int i = 0; i < 8; ++i) creg2[i] = 0.f;

  // ---- phase-2 loop invariants: tile q owned by c == (g+3q)%13 ----
  int myq = -1;
#pragma unroll
  for (int q = 0; q < 4; ++q)
    if ((g + 3 * q) % 13 == c) myq = q;
  const bool act2 = (myq >= 0);
  const int colbase2 = (act2 ? myq : 0) * 32;
  const int mh = w >> 1, jh = w & 1;
  const int j5 = colbase2 + jh * 16 + l16;
  const unsigned short* Wp5 = W5 + (size_t)j5 * 928 + quad * 8;
  const unsigned short* Ap5 = ls + (mh * 16 + l16) * 936 + quad * 8;
  float bi5 = 0.f, bf5 = 0.f, bg5 = 0.f, bo5 = 0.f;
  if (act2) { bi5 = b5[j5]; bf5 = b5[128 + j5]; bg5 = b5[256 + j5]; bo5 = b5[384 + j5]; }
  float creg3[4];
#pragma unroll
  for (int i = 0; i < 4; ++i) creg3[i] = 0.f;

  int* fA = flags + (size_t)(g * 17) * 16;        // 13 A-flags, 64B apart
  int* fB = flags + (size_t)(g * 17 + 13) * 16;   // 4 B-flags, 64B apart

  // init persistent l3 state from encoder output (LLC-coherent reads)
  for (int i = tid; i < 640; i += 256) {
    hl3p[i] = ldc4f(hl30 + (size_t)rowbase1 * 20 + i);
    cl3p[i] = ldc4f(cl30 + (size_t)rowbase1 * 20 + i);
  }
  __syncthreads();

  for (int t = 0; t < 256; ++t) {
    const int p = t & 1;
    const unsigned short* h2_in = h2buf + (size_t)p * 819200;
    unsigned short* h2_out = h2buf + (size_t)(1 - p) * 819200;
    const unsigned short* h3_in = h3buf + (size_t)p * 131072;
    unsigned short* h3_out = h3buf + (size_t)(1 - p) * 131072;

    // ================= phase 1: down + l3 (scalar) + l4 (MFMA) =============
    if (t > 0) {  // stage h3_prev tile (32x128 bf16) via coherent 8B loads
      unsigned long long tH[4];
#pragma unroll
      for (int k = 0; k < 4; ++k)
        tH[k] = ldc8((const unsigned long long*)h3_in + (size_t)rowbase1 * 32 +
                     tid + k * 256);
#pragma unroll
      for (int k = 0; k < 4; ++k)
        ((unsigned long long*)lsH3p)[tid + k * 256] = tH[k];
    }
    __syncthreads();
    if (t == 0) {
      for (int i = tid; i < 640; i += 256) {
        int bb = i / 20, k = i % 20;
        lsOut[i] = out0[(size_t)(rowbase1 + bb) * 20 + k];
      }
    } else {  // out = h3_prev @ dW^T + db
      for (int i = tid; i < 640; i += 256) {
        int bb = i / 20, k = i % 20;
        const float* wr = dW + k * 128;
        const unsigned short* hr = lsH3p + bb * 128;
        float s = db[k];
        for (int jj = 0; jj < 128; ++jj) s += bf2f(hr[jj]) * wr[jj];
        lsOut[i] = s;
      }
    }
    __syncthreads();
    for (int i = tid; i < 2560; i += 256) {  // l3 gates, K = [out(20)|hl3(20)]
      int bb = i / 80, n = i % 80;
      const float* wr = W3 + n * 40;
      const float* ob = lsOut + bb * 20;
      const float* hp = hl3p + bb * 20;
      float s = b3[n];
      for (int k = 0; k < 20; ++k) s += ob[k] * wr[k];
      for (int k = 0; k < 20; ++k) s += hp[k] * wr[20 + k];
      lsGates[i] = s;
    }
    __syncthreads();
    for (int i = tid; i < 640; i += 256) {  // l3 cell (updates persistent LDS)
      int bb = i / 20, jj = i % 20;
      const float* gg = lsGates + bb * 80;
      float iv = sigm(gg[jj]), fv = sigm(gg[20 + jj]);
      float gv = tanh_f(gg[40 + jj]), ov = sigm(gg[60 + jj]);
      float cc = fv * cl3p[i] + iv * gv;
      cl3p[i] = cc;
      hl3p[i] = ov * tanh_f(cc);
    }
    __syncthreads();
    // stage A: cols 0..19 = h_new, 20..23 = 0, 24..823 = h2_prev, 824..839 = 0
    {
      unsigned long long tA[25];
#pragma unroll
      for (int k = 0; k < 25; ++k) {
        int i = tid + k * 256;
        int bb = i / 200, s2 = i % 200;
        tA[k] = ldc8((const unsigned long long*)h2_in +
                     (size_t)(rowbase1 + bb) * 200 + s2);
      }
#pragma unroll
      for (int k = 0; k < 25; ++k) {
        int i = tid + k * 256;
        int bb = i / 200, s2 = i % 200;
        *(unsigned long long*)(ls + bb * 840 + 24 + s2 * 4) = tA[k];
      }
    }
    for (int i = tid; i < 640; i += 256) {
      int bb = i / 20, jj = i % 20;
      ls[bb * 840 + jj] = f2bf(hl3p[i]);
    }
    for (int i = tid; i < 640; i += 256) {
      int bb = i / 20, z = i % 20;
      int col = (z < 4) ? (20 + z) : (820 + z);
      ls[bb * 840 + col] = 0;
    }
    __syncthreads();
    float hreg[8];
    if (act1) {
      f32x4 acc[2][4];
#pragma unroll
      for (int mt = 0; mt < 2; ++mt)
#pragma unroll
        for (int gq = 0; gq < 4; ++gq) acc[mt][gq] = (f32x4){0.f, 0.f, 0.f, 0.f};
      for (int kc = 0; kc < 26; ++kc) {
        const int ko = kc * 32;
        bf16x8 a0 = *(const bf16x8*)(A0 + ko);
        bf16x8 a1 = *(const bf16x8*)(A1 + ko);
        bf16x8 bv0 = *(const bf16x8*)(Wp4 + (size_t)0 * 665600 + ko);
        bf16x8 bv1 = *(const bf16x8*)(Wp4 + (size_t)1 * 665600 + ko);
        bf16x8 bv2 = *(const bf16x8*)(Wp4 + (size_t)2 * 665600 + ko);
        bf16x8 bv3 = *(const bf16x8*)(Wp4 + (size_t)3 * 665600 + ko);
        acc[0][0] = __builtin_amdgcn_mfma_f32_16x16x32_bf16(a0, bv0, acc[0][0], 0, 0, 0);
        acc[1][0] = __builtin_amdgcn_mfma_f32_16x16x32_bf16(a1, bv0, acc[1][0], 0, 0, 0);
        acc[0][1] = __builtin_amdgcn_mfma_f32_16x16x32_bf16(a0, bv1, acc[0][1], 0, 0, 0);
        acc[1][1] = __builtin_amdgcn_mfma_f32_16x16x32_bf16(a1, bv1, acc[1][1], 0, 0, 0);
        acc[0][2] = __builtin_amdgcn_mfma_f32_16x16x32_bf16(a0, bv2, acc[0][2], 0, 0, 0);
        acc[1][2] = __builtin_amdgcn_mfma_f32_16x16x32_bf16(a1, bv2, acc[1][2], 0, 0, 0);
        acc[0][3] = __builtin_amdgcn_mfma_f32_16x16x32_bf16(a0, bv3, acc[0][3], 0, 0, 0);
        acc[1][3] = __builtin_amdgcn_mfma_f32_16x16x32_bf16(a1, bv3, acc[1][3], 0, 0, 0);
      }
#pragma unroll
      for (int mt = 0; mt < 2; ++mt) {
#pragma unroll
        for (int r = 0; r < 4; ++r) {
          float iv = sigm(acc[mt][0][r] + bi4);
          float fv = sigm(acc[mt][1][r] + bf4);
          float gv = tanh_f(acc[mt][2][r] + bg4);
          float ov = sigm(acc[mt][3][r] + bo4);
          float cc = fv * creg2[mt * 4 + r] + iv * gv;
          creg2[mt * 4 + r] = cc;
          hreg[mt * 4 + r] = ov * tanh_f(cc);
        }
      }
    }
    __syncthreads();   // all MFMA reads of ls done -> reuse ls as h2-out stage
    if (act1) {
#pragma unroll
      for (int mt = 0; mt < 2; ++mt)
#pragma unroll
        for (int r = 0; r < 4; ++r) {
          int row = mt * 16 + quad * 4 + r;
          ls[row * 64 + jwl + l16] = f2bf(hreg[mt * 4 + r]);
        }
    }
    __syncthreads();
#pragma unroll
    for (int k = 0; k < 2; ++k) {  // vectorized coherent store of h2 tile
      int u = tid + k * 256;       // u16[32][64] -> 512 8B units
      int row = u >> 4, cu = u & 15;
      if (cb + cu * 4 < 800)
        stc8((unsigned long long*)h2_out + (size_t)(rowbase1 + row) * 200 +
                 (cb >> 2) + cu,
             ((const unsigned long long*)ls)[u]);
    }
    __syncthreads();   // drains vmcnt in all waves before flag store
    if (tid == 0)
      __hip_atomic_store(&fA[c * 16], t + 1, __ATOMIC_RELAXED,
                         __HIP_MEMORY_SCOPE_AGENT);

    // ================= phase 2 (owner blocks): l5 (MFMA) + output ==========
    if (act2) {
      if (tid < 13) waitFlag(&fA[tid * 16], t + 1);
      __syncthreads();
      {
        unsigned long long tB[25], tC[4];
#pragma unroll
        for (int k = 0; k < 25; ++k) {
          int i = tid + k * 256;
          int bb = i / 200, s2 = i % 200;
          tB[k] = ldc8((const unsigned long long*)h2_out +
                       (size_t)(rowbase1 + bb) * 200 + s2);
        }
#pragma unroll
        for (int k = 0; k < 4; ++k)
          tC[k] = ldc8((const unsigned long long*)h3_in + (size_t)rowbase1 * 32 +
                       tid + k * 256);
#pragma unroll
        for (int k = 0; k < 25; ++k) {
          int i = tid + k * 256;
          int bb = i / 200, s2 = i % 200;
          *(unsigned long long*)(ls + bb * 936 + s2 * 4) = tB[k];
        }
#pragma unroll
        for (int k = 0; k < 4; ++k) {
          int i = tid + k * 256;
          int bb = i >> 5, s2 = i & 31;
          *(unsigned long long*)(ls + bb * 936 + 800 + s2 * 4) = tC[k];
        }
      }
      {
        int bb = tid >> 3, z = tid & 7;   // zero pad cols 928..935
        ls[bb * 936 + 928 + z] = 0;
      }
      __syncthreads();
      f32x4 acc[4];
#pragma unroll
      for (int gq = 0; gq < 4; ++gq) acc[gq] = (f32x4){0.f, 0.f, 0.f, 0.f};
      for (int kc = 0; kc < 29; ++kc) {
        const int ko = kc * 32;
        bf16x8 a = *(const bf16x8*)(Ap5 + ko);
        bf16x8 bv0 = *(const bf16x8*)(Wp5 + (size_t)0 * 118784 + ko);
        bf16x8 bv1 = *(const bf16x8*)(Wp5 + (size_t)1 * 118784 + ko);
        bf16x8 bv2 = *(const bf16x8*)(Wp5 + (size_t)2 * 118784 + ko);
        bf16x8 bv3 = *(const bf16x8*)(Wp5 + (size_t)3 * 118784 + ko);
        acc[0] = __builtin_amdgcn_mfma_f32_16x16x32_bf16(a, bv0, acc[0], 0, 0, 0);
        acc[1] = __builtin_amdgcn_mfma_f32_16x16x32_bf16(a, bv1, acc[1], 0, 0, 0);
        acc[2] = __builtin_amdgcn_mfma_f32_16x16x32_bf16(a, bv2, acc[2], 0, 0, 0);
        acc[3] = __builtin_amdgcn_mfma_f32_16x16x32_bf16(a, bv3, acc[3], 0, 0, 0);
      }
      float hreg3[4];
#pragma unroll
      for (int r = 0; r < 4; ++r) {
        int bg = rowbase1 + mh * 16 + quad * 4 + r;
        float iv = sigm(acc[0][r] + bi5);
        float fv = sigm(acc[1][r] + bf5);
        float gv = tanh_f(acc[2][r] + bg5);
        float ov = sigm(acc[3][r] + bo5);
        float cc = fv * creg3[r] + iv * gv;
        creg3[r] = cc;
        float h = ov * tanh_f(cc);
        hreg3[r] = h;
        dout[(size_t)t * 131072 + (size_t)bg * 128 + j5] = h;  // final output
      }
      __syncthreads();   // MFMA reads of ls done -> reuse as h3-out stage
#pragma unroll
      for (int r = 0; r < 4; ++r) {
        int row = mh * 16 + quad * 4 + r;
        ls[row * 32 + jh * 16 + l16] = f2bf(hreg3[r]);
      }
      __syncthreads();
      {
        int u = tid;                 // u16[32][32] -> 256 8B units
        if (u < 256) {
          int row = u >> 3, cu = u & 7;
          stc8((unsigned long long*)h3_out + (size_t)(rowbase1 + row) * 32 +
                   (colbase2 >> 2) + cu,
               ((const unsigned long long*)ls)[u]);
        }
      }
      __syncthreads();   // drain vmcnt before flag store
      if (tid == 0)
        __hip_atomic_store(&fB[myq * 16], t + 1, __ATOMIC_RELAXED,
                           __HIP_MEMORY_SCOPE_AGENT);
    }

    // ---- all blocks of the group wait for the 4 B-flags -------------------
    if (tid < 4) waitFlag(&fB[tid * 16], t + 1);
    __syncthreads();
  }
}

extern "C" void kernel_launch(void* const* d_in, const int* in_sizes, int n_in,
                              void* d_out, int out_size, void* d_ws, size_t ws_size,
                              hipStream_t stream) {
  (void)in_sizes; (void)n_in; (void)out_size; (void)ws_size;
  const float* x   = (const float*)d_in[0];
  const float* w1i = (const float*)d_in[1];
  const float* w1h = (const float*)d_in[2];
  const float* b1i = (const float*)d_in[3];
  const float* b1h = (const float*)d_in[4];
  const float* w2i = (const float*)d_in[5];
  const float* w2h = (const float*)d_in[6];
  const float* b2i = (const float*)d_in[7];
  const float* b2h = (const float*)d_in[8];
  const float* w3i = (const float*)d_in[9];
  const float* w3h = (const float*)d_in[10];
  const float* b3i = (const float*)d_in[11];
  const float* b3h = (const float*)d_in[12];
  const float* w4i = (const float*)d_in[13];
  const float* w4h = (const float*)d_in[14];
  const float* b4i = (const float*)d_in[15];
  const float* b4h = (const float*)d_in[16];
  const float* w5i = (const float*)d_in[17];
  const float* w5h = (const float*)d_in[18];
  const float* b5i = (const float*)d_in[19];
  const float* b5h = (const float*)d_in[20];
  const float* idW = (const float*)d_in[21];
  const float* idb = (const float*)d_in[22];
  const float* dW  = (const float*)d_in[23];
  const float* db  = (const float*)d_in[24];
  float* out = (float*)d_out;

  char* ws = (char*)d_ws;
  size_t off = 0;
  auto alloc = [&](size_t bytes) -> void* {
    void* p = ws + off;
    off = (off + bytes + 255) & ~(size_t)255;
    return p;
  };
  unsigned short* W4 = (unsigned short*)alloc(3200 * 832 * 2);
  unsigned short* W5 = (unsigned short*)alloc(512 * 928 * 2);
  float* W1 = (float*)alloc(240 * 192 * 4);
  float* W2 = (float*)alloc(80 * 80 * 4);
  float* W3 = (float*)alloc(80 * 40 * 4);
  float* b4 = (float*)alloc(3200 * 4);
  float* b5 = (float*)alloc(512 * 4);
  float* b1 = (float*)alloc(240 * 4);
  float* b2 = (float*)alloc(80 * 4);
  float* b3 = (float*)alloc(80 * 4);
  unsigned short* h2buf = (unsigned short*)alloc(2 * 1024 * 800 * 2);
  unsigned short* h3buf = (unsigned short*)alloc(2 * 1024 * 128 * 2);
  float* hl3 = (float*)alloc(1024 * 20 * 4);
  float* cl3 = (float*)alloc(1024 * 20 * 4);
  float* out0 = (float*)alloc(1024 * 20 * 4);
  int* flags = (int*)alloc(8704 * 4);   // 32 groups x 17 slots x 64B

  kPrep<<<dim3(4096), dim3(256), 0, stream>>>(
      w4i, w4h, b4i, b4h, w5i, w5h, b5i, b5h, w1i, w1h, b1i, b1h,
      w2i, w2h, b2i, b2h, w3i, w3h, b3i, b3h,
      W4, W5, W1, W2, W3, b4, b5, b1, b2, b3);
  kZero<<<dim3(2048), dim3(256), 0, stream>>>((unsigned int*)h2buf,
                                              (unsigned int*)h3buf, flags);
  kEnc<<<dim3(256), dim3(256), 0, stream>>>(x, W1, b1, W2, b2, idW, idb,
                                            hl3, cl3, out0, out + 33554432);
  kDec<<<dim3(416), dim3(256), 0, stream>>>(
      W4, b4, W5, b5, W3, b3, dW, db, out0, hl3, cl3,
      h2buf, h3buf, out, flags);
}